// Round 12
// baseline (552.387 us; speedup 1.0000x reference)
//
#include <hip/hip_runtime.h>

// Problem constants (from reference): N=100000, H=20000, E=1600000, D=64, L=3, F=256
#define HYP 20000
#define NLAYER 3
// Bucket-sort geometry: ids fit 15 bits (H=20000) / 17 bits (N=100000).
#define NB_H 313
#define NB_N 391
#define PT 4096

typedef __attribute__((ext_vector_type(8))) short short8;
typedef __attribute__((ext_vector_type(4))) float floatx4;

static __device__ __forceinline__ unsigned short f2bf(float f){
  union { float f; unsigned u; } v; v.f = f;
  unsigned r = v.u + 0x7FFF + ((v.u >> 16) & 1);
  return (unsigned short)(r >> 16);
}

// ---- CSR build, stage 1: global bucket histogram (LDS-staged) ----
__global__ __launch_bounds__(256) void k_hist(const int* __restrict__ src,
    const int* __restrict__ dst, int E, int* __restrict__ bh, int* __restrict__ bn){
  __shared__ int lh[NB_H + NB_N];
  int tid = threadIdx.x;
  for (int i = tid; i < NB_H + NB_N; i += 256) lh[i] = 0;
  __syncthreads();
  for (int i = blockIdx.x*256 + tid; i < E; i += gridDim.x*256){
    atomicAdd(&lh[dst[i] >> 6], 1);
    atomicAdd(&lh[NB_H + (src[i] >> 8)], 1);
  }
  __syncthreads();
  for (int i = tid; i < NB_H; i += 256) if (lh[i]) atomicAdd(&bh[i], lh[i]);
  for (int i = tid; i < NB_N; i += 256) if (lh[NB_H+i]) atomicAdd(&bn[i], lh[NB_H+i]);
}

// ---- stage 2: exclusive scan of bucket counts -> bucket starts + cursors ----
__global__ __launch_bounds__(256) void k_bscan(const int* __restrict__ bh,
    const int* __restrict__ bn, int* __restrict__ bstart_h, int* __restrict__ gcur_h,
    int* __restrict__ bstart_n, int* __restrict__ gcur_n){
  __shared__ int ssc[4];
  __shared__ int scarry;
  int tid = threadIdx.x, lane = tid & 63, wv = tid >> 6;
  if (tid == 0) scarry = 0;
  __syncthreads();
  for (int base = 0; base < NB_H; base += 256){
    int i = base + tid; int v = (i < NB_H) ? bh[i] : 0; int x = v;
    #pragma unroll
    for (int o = 1; o < 64; o <<= 1){ int t = __shfl_up(x,o,64); if (lane >= o) x += t; }
    if (lane == 63) ssc[wv] = x;
    __syncthreads();
    int add = (wv>0?ssc[0]:0)+(wv>1?ssc[1]:0)+(wv>2?ssc[2]:0);
    int c = scarry;
    if (i < NB_H){ int ex = c + add + x - v; bstart_h[i] = ex; gcur_h[i] = ex; }
    __syncthreads();
    if (tid == 255) scarry = c + ssc[0]+ssc[1]+ssc[2]+ssc[3];
    __syncthreads();
  }
  if (tid == 0){ bstart_h[NB_H] = scarry; scarry = 0; }
  __syncthreads();
  for (int base = 0; base < NB_N; base += 256){
    int i = base + tid; int v = (i < NB_N) ? bn[i] : 0; int x = v;
    #pragma unroll
    for (int o = 1; o < 64; o <<= 1){ int t = __shfl_up(x,o,64); if (lane >= o) x += t; }
    if (lane == 63) ssc[wv] = x;
    __syncthreads();
    int add = (wv>0?ssc[0]:0)+(wv>1?ssc[1]:0)+(wv>2?ssc[2]:0);
    int c = scarry;
    if (i < NB_N){ int ex = c + add + x - v; bstart_n[i] = ex; gcur_n[i] = ex; }
    __syncthreads();
    if (tid == 255) scarry = c + ssc[0]+ssc[1]+ssc[2]+ssc[3];
    __syncthreads();
  }
  if (tid == 0) bstart_n[NB_N] = scarry;
}

// ---- stage 3: LDS-staged radix partition, DUAL-SIDE in one launch ----
__global__ __launch_bounds__(256) void k_partition2(
    const int* __restrict__ esrc, const int* __restrict__ edst, int E, int nblk,
    int* __restrict__ gcur_h, unsigned* __restrict__ Ebuf_h,
    int* __restrict__ gcur_n, unsigned* __restrict__ Ebuf_n){
  __shared__ unsigned sst[PT];
  __shared__ int lh[NB_N], lpre[NB_N], gb[NB_N];
  __shared__ int ssc[4];
  __shared__ int scarry;
  int tid = threadIdx.x, lane = tid & 63, wv = tid >> 6;
  bool hside = (blockIdx.x < nblk);
  int bb = hside ? blockIdx.x : blockIdx.x - nblk;
  const int* keys = hside ? edst : esrc;
  const int* pays = hside ? esrc : edst;
  int keyshift = hside ? 17 : 15;
  int nb = hside ? NB_H : NB_N;
  int* gcur = hside ? gcur_h : gcur_n;
  unsigned* Ebuf = hside ? Ebuf_h : Ebuf_n;

  int base = bb*PT;
  int m = min(PT, E - base);
  for (int i = tid; i < nb; i += 256) lh[i] = 0;
  if (tid == 0) scarry = 0;
  __syncthreads();
  unsigned en[16]; int rk[16];
  #pragma unroll
  for (int j = 0; j < 16; ++j){
    int i = base + j*256 + tid;
    if (i < E){
      unsigned k = (unsigned)keys[i], p = (unsigned)pays[i];
      en[j] = (k << keyshift) | p;
      rk[j] = atomicAdd(&lh[en[j] >> 23], 1);
    } else { en[j] = 0; rk[j] = -1; }
  }
  __syncthreads();
  for (int b2 = 0; b2 < nb; b2 += 256){
    int i = b2 + tid; int v = (i < nb) ? lh[i] : 0; int x = v;
    #pragma unroll
    for (int o = 1; o < 64; o <<= 1){ int t = __shfl_up(x,o,64); if (lane >= o) x += t; }
    if (lane == 63) ssc[wv] = x;
    __syncthreads();
    int add = (wv>0?ssc[0]:0)+(wv>1?ssc[1]:0)+(wv>2?ssc[2]:0);
    int c = scarry;
    if (i < nb) lpre[i] = c + add + x - v;
    __syncthreads();
    if (tid == 255) scarry = c + ssc[0]+ssc[1]+ssc[2]+ssc[3];
    __syncthreads();
  }
  for (int i = tid; i < nb; i += 256) gb[i] = atomicAdd(&gcur[i], lh[i]);
  #pragma unroll
  for (int j = 0; j < 16; ++j){
    if (rk[j] >= 0){
      int bk = en[j] >> 23;
      sst[lpre[bk] + rk[j]] = en[j];
    }
  }
  __syncthreads();
  for (int j = tid; j < m; j += 256){
    unsigned e = sst[j];
    int bk = e >> 23;
    Ebuf[gb[bk] + (j - lpre[bk])] = e;
  }
}

// ---- stage 4: per-bucket CSR build, DUAL-SIDE in one launch ----
// n-side blocks additionally prescale their 256 node rows into xb0.
__global__ __launch_bounds__(256) void k_build2(
    const unsigned* __restrict__ Ebuf_h, const int* __restrict__ bstart_h,
    const unsigned* __restrict__ Ebuf_n, const int* __restrict__ bstart_n,
    int* __restrict__ off_h, float* __restrict__ is_h, int* __restrict__ csr_h,
    int* __restrict__ off_n, float* __restrict__ is_n, int* __restrict__ csr_n,
    const float* __restrict__ nf, unsigned short* __restrict__ xb,
    int Hn, int Nn){
  __shared__ int lcnt[256], lpre2[256], lcur[256];
  int tid = threadIdx.x, lane = tid & 63, wv = tid >> 6;
  bool hside = (blockIdx.x < NB_H);
  int b = hside ? blockIdx.x : blockIdx.x - NB_H;
  const unsigned* Ebuf = hside ? Ebuf_h : Ebuf_n;
  const int* bstart = hside ? bstart_h : bstart_n;
  int keyshift = hside ? 17 : 15;
  int ipb = hside ? 64 : 256;
  int paymask = hside ? 0x1FFFF : 0x7FFF;
  int limit = hside ? Hn : Nn;
  int* off = hside ? off_h : off_n;
  float* isv = hside ? is_h : is_n;
  int* csr = hside ? csr_h : csr_n;

  int base = bstart[b], m = bstart[b+1] - base;
  for (int i = tid; i < ipb; i += 256) lcnt[i] = 0;
  __syncthreads();
  for (int i = tid; i < m; i += 256){
    unsigned e = Ebuf[base + i];
    atomicAdd(&lcnt[(e >> keyshift) & (ipb-1)], 1);
  }
  __syncthreads();
  if (wv == 0){
    int carry = 0;
    for (int c = 0; c < ipb; c += 64){
      int li = c + lane;
      int v = lcnt[li]; int x = v;
      #pragma unroll
      for (int o = 1; o < 64; o <<= 1){ int t = __shfl_up(x,o,64); if (lane >= o) x += t; }
      int ex = carry + x - v;
      int id = b*ipb + li;
      if (id <= limit) off[id] = base + ex;
      if (id < limit) isv[id] = rsqrtf((float)(v > 0 ? v : 1));
      lpre2[li] = ex;
      carry += __shfl(x, 63, 64);
    }
  }
  for (int i = tid; i < ipb; i += 256) lcur[i] = 0;
  __syncthreads();
  for (int i = tid; i < m; i += 256){
    unsigned e = Ebuf[base + i];
    int li = (e >> keyshift) & (ipb-1);
    int pos = base + lpre2[li] + atomicAdd(&lcur[li], 1);
    csr[pos] = (int)(e & (unsigned)paymask);
  }
  // ---- folded prescale (n-side only): xb0 rows b*256..b*256+255 ----
  if (!hside){
    int nbase = b*256;
    for (int i = tid; i < 2048; i += 256){      // 256 rows x 8 chunks
      int li = i >> 3, kc = (i & 7)*8;
      int id = nbase + li;
      if (id < Nn){
        int v = lcnt[li];
        float s = rsqrtf((float)(v > 0 ? v : 1));
        float4 v0 = *(const float4*)&nf[(size_t)id*64 + kc];
        float4 v1 = *(const float4*)&nf[(size_t)id*64 + kc + 4];
        uint4 o;
        o.x = (unsigned)f2bf(v0.x*s) | ((unsigned)f2bf(v0.y*s) << 16);
        o.y = (unsigned)f2bf(v0.z*s) | ((unsigned)f2bf(v0.w*s) << 16);
        o.z = (unsigned)f2bf(v1.x*s) | ((unsigned)f2bf(v1.y*s) << 16);
        o.w = (unsigned)f2bf(v1.z*s) | ((unsigned)f2bf(v1.w*s) << 16);
        *(uint4*)&xb[(size_t)id*64 + kc] = o;
      }
    }
  }
}

// Convert FFN + output weights to bf16 transposed layouts (Wa/Wb consumed as
// fp32 by k_gatherHW, which bf16-converts into its own LDS).
__global__ void k_cvtall(const float* __restrict__ W1, const float* __restrict__ W2,
                         const float* __restrict__ Wo,
                         unsigned short* __restrict__ W1T, unsigned short* __restrict__ W2T,
                         unsigned short* __restrict__ WoT){
  int st = gridDim.x*blockDim.x;
  int t0 = blockIdx.x*blockDim.x + threadIdx.x;
  for (int j = t0; j < NLAYER*16384; j += st){
    int l = j >> 14, n = (j >> 6) & 255, k = j & 63;
    W1T[j] = f2bf(W1[l*16384 + k*256 + n]);
  }
  for (int j = t0; j < NLAYER*16384; j += st){
    int l = j >> 14, o = (j >> 8) & 63, kk = j & 255;
    W2T[j] = f2bf(W2[l*16384 + kk*64 + o]);
  }
  for (int j = t0; j < 4096; j += st){
    int n = (j >> 6) & 63, k = j & 63;
    WoT[j] = f2bf(Wo[k*64 + n]);
  }
}

// Contiguous 16B-chunk LDS staging of a pre-transposed [rows][64] bf16 matrix (pad-72).
template<int LSTR>
static __device__ __forceinline__ void stage64(const unsigned short* __restrict__ gsrc,
    unsigned short* __restrict__ ldst, int tid, int rows){
  int nch = rows*8;
  for (int idx = tid; idx < nch; idx += 256){
    int row = idx >> 3, kc = (idx & 7)*8;
    uint4 v = *(const uint4*)&gsrc[row*64 + kc];
    *(uint4*)&ldst[row*LSTR + kc] = v;
  }
}

static __device__ __forceinline__ short8 rdswz(const unsigned short* __restrict__ l,
    int row, int slot){
  return *(const short8*)&l[(row << 6) + ((((unsigned)(slot ^ row)) & 7u) << 3)];
}

#define ACCV(u) \
  a[0] += __uint_as_float(u.x << 16); a[1] += __uint_as_float(u.x & 0xFFFF0000u); \
  a[2] += __uint_as_float(u.y << 16); a[3] += __uint_as_float(u.y & 0xFFFF0000u); \
  a[4] += __uint_as_float(u.z << 16); a[5] += __uint_as_float(u.z & 0xFFFF0000u); \
  a[6] += __uint_as_float(u.w << 16); a[7] += __uint_as_float(u.w & 0xFFFF0000u);

#define ACCF(ua, ub) \
  a[0] += ua.x; a[1] += ua.y; a[2] += ua.z; a[3] += ua.w; \
  a[4] += ub.x; a[5] += ub.y; a[6] += ub.z; a[7] += ub.w;

#define MV8(acc, s, wv_) \
  acc[0] = fmaf(s, __uint_as_float(wv_.x << 16), acc[0]); \
  acc[1] = fmaf(s, __uint_as_float(wv_.x & 0xFFFF0000u), acc[1]); \
  acc[2] = fmaf(s, __uint_as_float(wv_.y << 16), acc[2]); \
  acc[3] = fmaf(s, __uint_as_float(wv_.y & 0xFFFF0000u), acc[3]); \
  acc[4] = fmaf(s, __uint_as_float(wv_.z << 16), acc[4]); \
  acc[5] = fmaf(s, __uint_as_float(wv_.z & 0xFFFF0000u), acc[5]); \
  acc[6] = fmaf(s, __uint_as_float(wv_.w << 16), acc[6]); \
  acc[7] = fmaf(s, __uint_as_float(wv_.w & 0xFFFF0000u), acc[7]);

// H-side gather FUSED with both 64x64 matmuls (Wa then Wb):
// z[e] = ((aggX[e]@Wa)*is_h + ba)*is_h @ Wb per hyperedge, fp32 throughout
// (fewer roundings than the split path, which rounded aggX and hh to bf16).
// Lane algebra (audited 4x): butterfly xor8/16/32 -> all lanes hold aggX[i8*8+t];
// mv1 partial over k-slice i8 for cols [g*8,+8), reduce xor1/2/4 -> h1[g*8+m];
// mv2 partial over j-slice g for cols [i8*8,+8), reduce xor8/16/32 -> z[i8*8+m].
// LDS weight stride 72 (rows 16B-aligned). ISOLATION: this is the ONLY change
// vs r11 (r10 proved LAST-fusion buggy alone; this tests the fold alone).
__global__ __launch_bounds__(256) void k_gatherHW(
    const unsigned short* __restrict__ feat, const int* __restrict__ csr,
    const int* __restrict__ off, const float* __restrict__ Waf,
    const float* __restrict__ bav_g, const float* __restrict__ Wbf,
    const float* __restrict__ ihy, float* __restrict__ zb, int nrows){
  __shared__ unsigned short sWa[64*72];
  __shared__ unsigned short sWb[64*72];
  int tid = threadIdx.x;
  for (int idx = tid; idx < 4096; idx += 256){
    int k = idx >> 6, j = idx & 63;
    sWa[k*72 + j] = f2bf(Waf[idx]);
    sWb[k*72 + j] = f2bf(Wbf[idx]);
  }
  int lane = tid & 63, wvi = tid >> 6;
  int g = lane >> 3, i8 = lane & 7;
  int ch = i8*8;
  float bav[8];
  #pragma unroll
  for (int m = 0; m < 8; ++m) bav[m] = bav_g[g*8 + m];
  __syncthreads();

  int r = blockIdx.x*4 + wvi, stride = gridDim.x*4;
  for (; r < nrows; r += stride){
    int b = off[r], e = off[r+1];
    float a[8] = {0,0,0,0,0,0,0,0};
    int t = b;
    for (; t + 32 <= e; t += 32){
      int s0 = csr[t + g];
      int s1 = csr[t + 8 + g];
      int s2 = csr[t + 16 + g];
      int s3 = csr[t + 24 + g];
      uint4 u0 = *(const uint4*)&feat[(size_t)s0*64 + ch];
      uint4 u1 = *(const uint4*)&feat[(size_t)s1*64 + ch];
      uint4 u2 = *(const uint4*)&feat[(size_t)s2*64 + ch];
      uint4 u3 = *(const uint4*)&feat[(size_t)s3*64 + ch];
      ACCV(u0); ACCV(u1); ACCV(u2); ACCV(u3);
    }
    for (; t + 16 <= e; t += 16){
      int s0 = csr[t + g];
      int s1 = csr[t + 8 + g];
      uint4 u0 = *(const uint4*)&feat[(size_t)s0*64 + ch];
      uint4 u1 = *(const uint4*)&feat[(size_t)s1*64 + ch];
      ACCV(u0); ACCV(u1);
    }
    for (; t < e; t += 8){
      int idx = t + g;
      bool valid = idx < e;
      int s = csr[valid ? idx : b];
      uint4 u = *(const uint4*)&feat[(size_t)s*64 + ch];
      if (!valid){ u.x = 0; u.y = 0; u.z = 0; u.w = 0; }
      ACCV(u);
    }
    #pragma unroll
    for (int o = 8; o <= 32; o <<= 1){
      #pragma unroll
      for (int m = 0; m < 8; ++m) a[m] += __shfl_xor(a[m], o, 64);
    }
    float ih = ihy[r];
    float p[8] = {0,0,0,0,0,0,0,0};
    #pragma unroll
    for (int tt = 0; tt < 8; ++tt){
      uint4 wv_ = *(const uint4*)&sWa[(i8*8 + tt)*72 + g*8];
      float at = a[tt];
      MV8(p, at, wv_);
    }
    #pragma unroll
    for (int o = 1; o <= 4; o <<= 1){
      #pragma unroll
      for (int m = 0; m < 8; ++m) p[m] += __shfl_xor(p[m], o, 64);
    }
    float hh[8];
    #pragma unroll
    for (int m = 0; m < 8; ++m) hh[m] = fmaf(p[m], ih, bav[m]) * ih;
    float q[8] = {0,0,0,0,0,0,0,0};
    #pragma unroll
    for (int tt = 0; tt < 8; ++tt){
      uint4 wv_ = *(const uint4*)&sWb[(g*8 + tt)*72 + i8*8];
      float ht = hh[tt];
      MV8(q, ht, wv_);
    }
    #pragma unroll
    for (int o = 8; o <= 32; o <<= 1){
      #pragma unroll
      for (int m = 0; m < 8; ++m) q[m] += __shfl_xor(q[m], o, 64);
    }
    if (g == 0){
      float4 w0; w0.x = q[0]; w0.y = q[1]; w0.z = q[2]; w0.w = q[3];
      float4 w1; w1.x = q[4]; w1.y = q[5]; w1.z = q[6]; w1.w = q[7];
      *(float4*)&zb[(size_t)r*64 + ch] = w0;
      *(float4*)&zb[(size_t)r*64 + ch + 4] = w1;
    }
  }
}

// Gather (N-side, r11-proven structure, fp32 input): 8 rows per wave, one 8-lane
// group per row, serial edge loop, 2 edges (4 loads) in flight per group, zero
// cross-lane reduction. Reads fp32 z rows (two float4 per edge), writes bf16 agg.
__global__ __launch_bounds__(256) void k_gatherN(const float* __restrict__ feat,
    const int* __restrict__ csr, const int* __restrict__ off,
    unsigned short* __restrict__ agg, int nrows){
  int lane = threadIdx.x & 63, wvi = threadIdx.x >> 6;
  int g = lane >> 3;          // row slot within wave (8 rows/wave)
  int ch = (lane & 7) * 8;    // this lane's 8-column chunk
  int wid = blockIdx.x*4 + wvi;
  int nw = gridDim.x*4;
  for (int r0 = wid*8; r0 < nrows; r0 += nw*8){
    int r = r0 + g;
    bool vr = (r < nrows);
    int b = 0, e = 0;
    if (vr){ b = off[r]; e = off[r+1]; }
    float a[8] = {0,0,0,0,0,0,0,0};
    int t = b;
    for (; t + 2 <= e; t += 2){
      int s0 = csr[t];
      int s1 = csr[t+1];
      float4 u0a = *(const float4*)&feat[(size_t)s0*64 + ch];
      float4 u0b = *(const float4*)&feat[(size_t)s0*64 + ch + 4];
      float4 u1a = *(const float4*)&feat[(size_t)s1*64 + ch];
      float4 u1b = *(const float4*)&feat[(size_t)s1*64 + ch + 4];
      ACCF(u0a, u0b); ACCF(u1a, u1b);
    }
    if (t < e){
      int s = csr[t];
      float4 ua = *(const float4*)&feat[(size_t)s*64 + ch];
      float4 ub = *(const float4*)&feat[(size_t)s*64 + ch + 4];
      ACCF(ua, ub);
    }
    if (vr){
      uint4 w;
      w.x = (unsigned)f2bf(a[0]) | ((unsigned)f2bf(a[1]) << 16);
      w.y = (unsigned)f2bf(a[2]) | ((unsigned)f2bf(a[3]) << 16);
      w.z = (unsigned)f2bf(a[4]) | ((unsigned)f2bf(a[5]) << 16);
      w.w = (unsigned)f2bf(a[6]) | ((unsigned)f2bf(a[7]) << 16);
      *(uint4*)&agg[(size_t)r*64 + ch] = w;
    }
  }
}

// Fused per-node pipeline, STAGE-ONCE / BARRIER-FREE LOOP, 1024-thread blocks.
// Wb folded upstream: prologue is pure VALU (P = z_agg*is_n + bb + hin).
// (LAST-fusion is permanently dead — r10 proved it corrupts results alone.)
__global__ __launch_bounds__(1024) void k_fused(
    const unsigned short* __restrict__ aggb,
    const float* __restrict__ bbg,
    const float* __restrict__ isn,
    const float* __restrict__ hin,
    const float* __restrict__ g1v, const float* __restrict__ be1v,
    const unsigned short* __restrict__ W1T, const float* __restrict__ b1g,
    const unsigned short* __restrict__ W2T, const float* __restrict__ b2g,
    const float* __restrict__ g2v, const float* __restrict__ be2v,
    float* __restrict__ Outp, unsigned short* __restrict__ Qs, int nrows)
{
  __shared__ unsigned short sW1[4*64*64];   // W1, 4 quarters (swizzled)
  __shared__ unsigned short sW2[4*64*64];   // W2, 4 quarters (swizzled)
  __shared__ unsigned short sPH[16*16*72];  // per-wave scratch (P / H1 round-trips)
  int tid = threadIdx.x;
  int lane = tid & 63, w = tid >> 6;
  int quad = lane >> 4, n16 = lane & 15;
  unsigned short* myP = &sPH[w*16*72];

  // ---- stage 8 weight tiles once (4096 16B chunks across 1024 threads) ----
  for (int c = tid; c < 4096; c += 1024){
    int tile = c >> 9, cc = c & 511;
    int row = cc >> 3, s = cc & 7;
    const unsigned short* src; unsigned short* dst; int gs;
    if (tile < 4){ src = W1T + tile*64*64; gs = 64; dst = sW1 + tile*4096; }
    else { int q = tile-4; src = W2T + q*64; gs = 256; dst = sW2 + q*4096; }
    uint4 v = *(const uint4*)&src[row*gs + s*8];
    *(uint4*)&dst[(row << 6) + ((((unsigned)(s ^ row)) & 7u) << 3)] = v;
  }

  // hoist per-lane constants (independent of tile)
  float bbv[4], g1l[4], be1l[4], b2v[4], g2l[4], be2l[4];
  #pragma unroll
  for (int ot = 0; ot < 4; ++ot){
    bbv[ot] = bbg[ot*16 + n16];
    g1l[ot] = g1v[ot*16 + n16];  be1l[ot] = be1v[ot*16 + n16];
    b2v[ot] = b2g[ot*16 + n16];
    g2l[ot] = g2v[ot*16 + n16];  be2l[ot] = be2v[ot*16 + n16];
  }
  float b1v[4][4];
  #pragma unroll
  for (int q = 0; q < 4; ++q)
    #pragma unroll
    for (int c2 = 0; c2 < 4; ++c2)   // c2 = ck2*2 + nt
      b1v[q][c2] = b1g[q*64 + c2*16 + n16];

  __syncthreads();   // the ONLY block barrier

  int ngrp = (nrows + 15) >> 4;
  int wwid = blockIdx.x*16 + w;
  int nw = gridDim.x*16;

  for (int grp = wwid; grp < ngrp; grp += nw){
    int rb = grp*16;

    float pP[4][4];
    float isr[4];
    #pragma unroll
    for (int r = 0; r < 4; ++r) isr[r] = isn[min(rb + quad*4 + r, nrows-1)];
    // prologue: P = z_agg*is_n + bb + hin (no MFMA — Wb folded upstream)
    #pragma unroll
    for (int ot = 0; ot < 4; ++ot){
      #pragma unroll
      for (int r = 0; r < 4; ++r){
        int rr = min(rb + quad*4 + r, nrows-1);
        float zf = __uint_as_float(((unsigned)aggb[(size_t)rr*64 + ot*16 + n16]) << 16);
        pP[ot][r] = fmaf(zf, isr[r], bbv[ot]) + hin[(size_t)rr*64 + ot*16 + n16];
      }
    }
    // LN1
    #pragma unroll
    for (int r = 0; r < 4; ++r){
      float sv = (pP[0][r] + pP[1][r]) + (pP[2][r] + pP[3][r]);
      float q = fmaf(pP[0][r], pP[0][r], pP[1][r]*pP[1][r]) +
                fmaf(pP[2][r], pP[2][r], pP[3][r]*pP[3][r]);
      #pragma unroll
      for (int o = 8; o >= 1; o >>= 1){
        sv += __shfl_xor(sv, o, 64);
        q  += __shfl_xor(q, o, 64);
      }
      float mu = sv*(1.f/64.f);
      float var = fmaf(-mu, mu, q*(1.f/64.f));
      float rs = rsqrtf(var + 1e-5f);
      #pragma unroll
      for (int ot = 0; ot < 4; ++ot)
        pP[ot][r] = fmaf((pP[ot][r]-mu)*rs, g1l[ot], be1l[ot]);
    }
    // C-layout -> A-layout via per-wave LDS round trip (wave-private)
    #pragma unroll
    for (int ot = 0; ot < 4; ++ot)
      #pragma unroll
      for (int r = 0; r < 4; ++r)
        myP[(quad*4 + r)*72 + ot*16 + n16] = f2bf(pP[ot][r]);
    short8 p0 = *(const short8*)&myP[n16*72 + quad*8];
    short8 p1 = *(const short8*)&myP[n16*72 + 32 + quad*8];

    // FFN: all weights LDS-resident, no barriers.
    floatx4 acc2[4];
    #pragma unroll
    for (int t = 0; t < 4; ++t) acc2[t] = (floatx4){0.f,0.f,0.f,0.f};

    #pragma unroll
    for (int q = 0; q < 4; ++q){
      const unsigned short* sA = sW1 + q*4096;
      const unsigned short* sB = sW2 + q*4096;
      #pragma unroll
      for (int ck2 = 0; ck2 < 2; ++ck2){
        #pragma unroll
        for (int nt = 0; nt < 2; ++nt){
          int nl = ck2*32 + nt*16 + n16;
          floatx4 c = (floatx4){0.f,0.f,0.f,0.f};
          short8 b0 = rdswz(sA, nl, quad);
          short8 b1f = rdswz(sA, nl, 4+quad);
          c = __builtin_amdgcn_mfma_f32_16x16x32_bf16(p0, b0, c, 0, 0, 0);
          c = __builtin_amdgcn_mfma_f32_16x16x32_bf16(p1, b1f, c, 0, 0, 0);
          float bb = b1v[q][ck2*2 + nt];
          #pragma unroll
          for (int r = 0; r < 4; ++r){
            float h = fmaxf(c[r] + bb, 0.f);
            myP[(quad*4 + r)*40 + nt*16 + n16] = f2bf(h);
          }
        }
        short8 a2 = *(const short8*)&myP[n16*40 + quad*8];
        #pragma unroll
        for (int ot = 0; ot < 4; ++ot){
          short8 b2f = rdswz(sB, ot*16+n16, ck2*4 + quad);
          acc2[ot] = __builtin_amdgcn_mfma_f32_16x16x32_bf16(a2, b2f, acc2[ot], 0, 0, 0);
        }
      }
    }

    // epilogue-2 (LN2 + dual store)
    float pre[4][4];
    #pragma unroll
    for (int ot = 0; ot < 4; ++ot)
      #pragma unroll
      for (int r = 0; r < 4; ++r)
        pre[ot][r] = acc2[ot][r] + b2v[ot] + pP[ot][r];
    #pragma unroll
    for (int r = 0; r < 4; ++r){
      float sv = (pre[0][r] + pre[1][r]) + (pre[2][r] + pre[3][r]);
      float q = fmaf(pre[0][r], pre[0][r], pre[1][r]*pre[1][r]) +
                fmaf(pre[2][r], pre[2][r], pre[3][r]*pre[3][r]);
      #pragma unroll
      for (int o = 8; o >= 1; o >>= 1){
        sv += __shfl_xor(sv, o, 64);
        q  += __shfl_xor(q, o, 64);
      }
      float mu = sv*(1.f/64.f);
      float var = fmaf(-mu, mu, q*(1.f/64.f));
      float rs = rsqrtf(var + 1e-5f);
      int rr = rb + quad*4 + r;
      if (rr < nrows){
        float isr2 = isn[rr];
        #pragma unroll
        for (int ot = 0; ot < 4; ++ot){
          float ov = fmaf((pre[ot][r]-mu)*rs, g2l[ot], be2l[ot]);
          Outp[(size_t)rr*64 + ot*16 + n16] = ov;
          Qs[(size_t)rr*64 + ot*16 + n16] = f2bf(ov * isr2);
        }
      }
    }
  }
}

// MFMA final: out = LN(Q, gF, bF) @ Wo + bo
__global__ __launch_bounds__(256) void k_final(const float* __restrict__ Q,
    const unsigned short* __restrict__ WoT, const float* __restrict__ bog,
    const float* __restrict__ gF, const float* __restrict__ bF,
    float* __restrict__ out, int nrows){
  __shared__ unsigned short sWb[64*72];
  int tid = threadIdx.x;
  int lane = tid & 63, w = tid >> 6;
  int quad = lane >> 4, n16 = lane & 15;
  stage64<72>(WoT, sWb, tid, 64);
  __syncthreads();
  int rowbase = blockIdx.x*64 + w*16;
  int arow = min(rowbase + n16, nrows-1);
  float4 q0 = *(const float4*)&Q[(size_t)arow*64 + quad*8];
  float4 q1 = *(const float4*)&Q[(size_t)arow*64 + quad*8 + 4];
  float4 q2 = *(const float4*)&Q[(size_t)arow*64 + 32 + quad*8];
  float4 q3 = *(const float4*)&Q[(size_t)arow*64 + 32 + quad*8 + 4];
  float s = (q0.x+q0.y+q0.z+q0.w) + (q1.x+q1.y+q1.z+q1.w)
          + (q2.x+q2.y+q2.z+q2.w) + (q3.x+q3.y+q3.z+q3.w);
  float qq = (q0.x*q0.x+q0.y*q0.y+q0.z*q0.z+q0.w*q0.w)
           + (q1.x*q1.x+q1.y*q1.y+q1.z*q1.z+q1.w*q1.w)
           + (q2.x*q2.x+q2.y*q2.y+q2.z*q2.z+q2.w*q2.w)
           + (q3.x*q3.x+q3.y*q3.y+q3.z*q3.z+q3.w*q3.w);
  s += __shfl_xor(s, 16, 64);  qq += __shfl_xor(qq, 16, 64);
  s += __shfl_xor(s, 32, 64);  qq += __shfl_xor(qq, 32, 64);
  float mu = s*(1.f/64.f);
  float var = fmaf(-mu, mu, qq*(1.f/64.f));
  float rs = rsqrtf(var + 1e-5f);
  float4 g0 = *(const float4*)&gF[quad*8];
  float4 g1 = *(const float4*)&gF[quad*8 + 4];
  float4 g2 = *(const float4*)&gF[32 + quad*8];
  float4 g3 = *(const float4*)&gF[32 + quad*8 + 4];
  float4 f0 = *(const float4*)&bF[quad*8];
  float4 f1 = *(const float4*)&bF[quad*8 + 4];
  float4 f2 = *(const float4*)&bF[32 + quad*8];
  float4 f3 = *(const float4*)&bF[32 + quad*8 + 4];
  short8 a0, a1;
  a0[0]=f2bf(fmaf((q0.x-mu)*rs, g0.x, f0.x)); a0[1]=f2bf(fmaf((q0.y-mu)*rs, g0.y, f0.y));
  a0[2]=f2bf(fmaf((q0.z-mu)*rs, g0.z, f0.z)); a0[3]=f2bf(fmaf((q0.w-mu)*rs, g0.w, f0.w));
  a0[4]=f2bf(fmaf((q1.x-mu)*rs, g1.x, f1.x)); a0[5]=f2bf(fmaf((q1.y-mu)*rs, g1.y, f1.y));
  a0[6]=f2bf(fmaf((q1.z-mu)*rs, g1.z, f1.z)); a0[7]=f2bf(fmaf((q1.w-mu)*rs, g1.w, f1.w));
  a1[0]=f2bf(fmaf((q2.x-mu)*rs, g2.x, f2.x)); a1[1]=f2bf(fmaf((q2.y-mu)*rs, g2.y, f2.y));
  a1[2]=f2bf(fmaf((q2.z-mu)*rs, g2.z, f2.z)); a1[3]=f2bf(fmaf((q2.w-mu)*rs, g2.w, f2.w));
  a1[4]=f2bf(fmaf((q3.x-mu)*rs, g3.x, f3.x)); a1[5]=f2bf(fmaf((q3.y-mu)*rs, g3.y, f3.y));
  a1[6]=f2bf(fmaf((q3.z-mu)*rs, g3.z, f3.z)); a1[7]=f2bf(fmaf((q3.w-mu)*rs, g3.w, f3.w));
  #pragma unroll
  for (int ot = 0; ot < 4; ++ot){
    floatx4 c = (floatx4){0.f,0.f,0.f,0.f};
    short8 b0 = *(const short8*)&sWb[(ot*16+n16)*72 + quad*8];
    short8 b1 = *(const short8*)&sWb[(ot*16+n16)*72 + 32 + quad*8];
    c = __builtin_amdgcn_mfma_f32_16x16x32_bf16(a0, b0, c, 0, 0, 0);
    c = __builtin_amdgcn_mfma_f32_16x16x32_bf16(a1, b1, c, 0, 0, 0);
    float bol = bog[ot*16 + n16];
    #pragma unroll
    for (int r = 0; r < 4; ++r){
      int rr = rowbase + quad*4 + r;
      if (rr < nrows) out[(size_t)rr*64 + ot*16 + n16] = c[r] + bol;
    }
  }
}

extern "C" void kernel_launch(void* const* d_in, const int* in_sizes, int n_in,
                              void* d_out, int out_size, void* d_ws, size_t ws_size,
                              hipStream_t stream){
  const float* nf   = (const float*)d_in[0];
  const int*   esrc = (const int*)d_in[1];
  const int*   edst = (const int*)d_in[2];
  const float* Wn2h = (const float*)d_in[4];
  const float* bn2h = (const float*)d_in[5];
  const float* Wh2n = (const float*)d_in[6];
  const float* bh2n = (const float*)d_in[7];
  const float* W1   = (const float*)d_in[8];
  const float* b1   = (const float*)d_in[9];
  const float* W2   = (const float*)d_in[10];
  const float* b2   = (const float*)d_in[11];
  const float* g1   = (const float*)d_in[12];
  const float* be1  = (const float*)d_in[13];
  const float* g2   = (const float*)d_in[14];
  const float* be2  = (const float*)d_in[15];
  const float* gF   = (const float*)d_in[16];
  const float* bF   = (const float*)d_in[17];
  const float* Wo   = (const float*)d_in[18];
  const float* bo   = (const float*)d_in[19];
  const int N = in_sizes[0] / 64;
  const int E = in_sizes[1];
  const int H = HYP;
  float* out = (float*)d_out;

  char* w = (char*)d_ws;
  auto carve = [&](size_t bytes) -> char* {
    char* p = w; w += (bytes + 255) & ~(size_t)255; return p;
  };
  int* bh = (int*)carve((size_t)(NB_H + NB_N)*4);
  int* bn = bh + NB_H;
  int* bstart_h = (int*)carve((size_t)(NB_H+1)*4);
  int* gcur_h   = (int*)carve((size_t)NB_H*4);
  int* bstart_n = (int*)carve((size_t)(NB_N+1)*4);
  int* gcur_n   = (int*)carve((size_t)NB_N*4);
  unsigned* Ebuf_h = (unsigned*)carve((size_t)E*4);
  unsigned* Ebuf_n = (unsigned*)carve((size_t)E*4);
  int*   off_h = (int*)carve((size_t)(H+1)*4);
  int*   off_n = (int*)carve((size_t)(N+1)*4);
  float* is_h  = (float*)carve((size_t)H*4);
  float* is_n  = (float*)carve((size_t)N*4);
  int*   csr_h = (int*)carve((size_t)E*4);
  int*   csr_n = (int*)carve((size_t)E*4);
  float* zbf   = (float*)carve((size_t)H*64*4);
  unsigned short* agghb = (unsigned short*)carve((size_t)N*64*2);
  float* Qb    = (float*)carve((size_t)N*64*4);
  unsigned short* xb0  = (unsigned short*)carve((size_t)N*64*2);
  unsigned short* Qs   = (unsigned short*)carve((size_t)N*64*2);
  unsigned short* W1g16 = (unsigned short*)carve((size_t)NLAYER*64*256*2);
  unsigned short* W2g16 = (unsigned short*)carve((size_t)NLAYER*256*64*2);
  unsigned short* Wog16 = (unsigned short*)carve((size_t)4096*2);

  hipMemsetAsync(bh, 0, (size_t)(NB_H + NB_N)*4, stream);
  k_cvtall<<<96, 256, 0, stream>>>(W1, W2, Wo, W1g16, W2g16, Wog16);
  k_hist<<<512, 256, 0, stream>>>(esrc, edst, E, bh, bn);
  k_bscan<<<1, 256, 0, stream>>>(bh, bn, bstart_h, gcur_h, bstart_n, gcur_n);
  const int nblk = (E + PT - 1)/PT;
  k_partition2<<<2*nblk, 256, 0, stream>>>(esrc, edst, E, nblk,
                                           gcur_h, Ebuf_h, gcur_n, Ebuf_n);
  k_build2<<<NB_H + NB_N, 256, 0, stream>>>(Ebuf_h, bstart_h, Ebuf_n, bstart_n,
                                            off_h, is_h, csr_h,
                                            off_n, is_n, csr_n,
                                            nf, xb0, H, N);

  const int NB64 = (N + 63)/64;
  for (int l = 0; l < NLAYER; ++l){
    const float* hin = (l == 0) ? nf : Qb;
    const unsigned short* hsrc = (l == 0) ? xb0 : Qs;
    k_gatherHW<<<2048, 256, 0, stream>>>(hsrc, csr_h, off_h,
                                         Wn2h + l*4096, bn2h + l*64, Wh2n + l*4096,
                                         is_h, zbf, H);
    k_gatherN<<<2048, 256, 0, stream>>>(zbf, csr_n, off_n, agghb, N);
    k_fused<<<256, 1024, 0, stream>>>(agghb, bh2n + l*64, is_n, hin,
                                      g1 + l*64, be1 + l*64,
                                      W1g16 + l*64*256, b1 + l*256,
                                      W2g16 + l*256*64, b2 + l*64,
                                      g2 + l*64, be2 + l*64, Qb, Qs, N);
  }
  k_final<<<NB64, 256, 0, stream>>>(Qb, Wog16, bo, gF, bF, out, N);
}

// Round 14
// 450.516 us; speedup vs baseline: 1.2261x; 1.2261x over previous
//
#include <hip/hip_runtime.h>

// Problem constants (from reference): N=100000, H=20000, E=1600000, D=64, L=3, F=256
#define HYP 20000
#define NLAYER 3
// Bucket-sort geometry: ids fit 15 bits (H=20000) / 17 bits (N=100000).
#define NB_H 313
#define NB_N 391
#define PT 4096

typedef __attribute__((ext_vector_type(8))) short short8;
typedef __attribute__((ext_vector_type(4))) float floatx4;

static __device__ __forceinline__ unsigned short f2bf(float f){
  union { float f; unsigned u; } v; v.f = f;
  unsigned r = v.u + 0x7FFF + ((v.u >> 16) & 1);
  return (unsigned short)(r >> 16);
}

// ---- CSR build, stage 1: global bucket histogram (LDS-staged) ----
__global__ __launch_bounds__(256) void k_hist(const int* __restrict__ src,
    const int* __restrict__ dst, int E, int* __restrict__ bh, int* __restrict__ bn){
  __shared__ int lh[NB_H + NB_N];
  int tid = threadIdx.x;
  for (int i = tid; i < NB_H + NB_N; i += 256) lh[i] = 0;
  __syncthreads();
  for (int i = blockIdx.x*256 + tid; i < E; i += gridDim.x*256){
    atomicAdd(&lh[dst[i] >> 6], 1);
    atomicAdd(&lh[NB_H + (src[i] >> 8)], 1);
  }
  __syncthreads();
  for (int i = tid; i < NB_H; i += 256) if (lh[i]) atomicAdd(&bh[i], lh[i]);
  for (int i = tid; i < NB_N; i += 256) if (lh[NB_H+i]) atomicAdd(&bn[i], lh[NB_H+i]);
}

// ---- stage 2: exclusive scan of bucket counts -> bucket starts + cursors ----
__global__ __launch_bounds__(256) void k_bscan(const int* __restrict__ bh,
    const int* __restrict__ bn, int* __restrict__ bstart_h, int* __restrict__ gcur_h,
    int* __restrict__ bstart_n, int* __restrict__ gcur_n){
  __shared__ int ssc[4];
  __shared__ int scarry;
  int tid = threadIdx.x, lane = tid & 63, wv = tid >> 6;
  if (tid == 0) scarry = 0;
  __syncthreads();
  for (int base = 0; base < NB_H; base += 256){
    int i = base + tid; int v = (i < NB_H) ? bh[i] : 0; int x = v;
    #pragma unroll
    for (int o = 1; o < 64; o <<= 1){ int t = __shfl_up(x,o,64); if (lane >= o) x += t; }
    if (lane == 63) ssc[wv] = x;
    __syncthreads();
    int add = (wv>0?ssc[0]:0)+(wv>1?ssc[1]:0)+(wv>2?ssc[2]:0);
    int c = scarry;
    if (i < NB_H){ int ex = c + add + x - v; bstart_h[i] = ex; gcur_h[i] = ex; }
    __syncthreads();
    if (tid == 255) scarry = c + ssc[0]+ssc[1]+ssc[2]+ssc[3];
    __syncthreads();
  }
  if (tid == 0){ bstart_h[NB_H] = scarry; scarry = 0; }
  __syncthreads();
  for (int base = 0; base < NB_N; base += 256){
    int i = base + tid; int v = (i < NB_N) ? bn[i] : 0; int x = v;
    #pragma unroll
    for (int o = 1; o < 64; o <<= 1){ int t = __shfl_up(x,o,64); if (lane >= o) x += t; }
    if (lane == 63) ssc[wv] = x;
    __syncthreads();
    int add = (wv>0?ssc[0]:0)+(wv>1?ssc[1]:0)+(wv>2?ssc[2]:0);
    int c = scarry;
    if (i < NB_N){ int ex = c + add + x - v; bstart_n[i] = ex; gcur_n[i] = ex; }
    __syncthreads();
    if (tid == 255) scarry = c + ssc[0]+ssc[1]+ssc[2]+ssc[3];
    __syncthreads();
  }
  if (tid == 0) bstart_n[NB_N] = scarry;
}

// ---- stage 3: LDS-staged radix partition, DUAL-SIDE in one launch ----
__global__ __launch_bounds__(256) void k_partition2(
    const int* __restrict__ esrc, const int* __restrict__ edst, int E, int nblk,
    int* __restrict__ gcur_h, unsigned* __restrict__ Ebuf_h,
    int* __restrict__ gcur_n, unsigned* __restrict__ Ebuf_n){
  __shared__ unsigned sst[PT];
  __shared__ int lh[NB_N], lpre[NB_N], gb[NB_N];
  __shared__ int ssc[4];
  __shared__ int scarry;
  int tid = threadIdx.x, lane = tid & 63, wv = tid >> 6;
  bool hside = (blockIdx.x < nblk);
  int bb = hside ? blockIdx.x : blockIdx.x - nblk;
  const int* keys = hside ? edst : esrc;
  const int* pays = hside ? esrc : edst;
  int keyshift = hside ? 17 : 15;
  int nb = hside ? NB_H : NB_N;
  int* gcur = hside ? gcur_h : gcur_n;
  unsigned* Ebuf = hside ? Ebuf_h : Ebuf_n;

  int base = bb*PT;
  int m = min(PT, E - base);
  for (int i = tid; i < nb; i += 256) lh[i] = 0;
  if (tid == 0) scarry = 0;
  __syncthreads();
  unsigned en[16]; int rk[16];
  #pragma unroll
  for (int j = 0; j < 16; ++j){
    int i = base + j*256 + tid;
    if (i < E){
      unsigned k = (unsigned)keys[i], p = (unsigned)pays[i];
      en[j] = (k << keyshift) | p;
      rk[j] = atomicAdd(&lh[en[j] >> 23], 1);
    } else { en[j] = 0; rk[j] = -1; }
  }
  __syncthreads();
  for (int b2 = 0; b2 < nb; b2 += 256){
    int i = b2 + tid; int v = (i < nb) ? lh[i] : 0; int x = v;
    #pragma unroll
    for (int o = 1; o < 64; o <<= 1){ int t = __shfl_up(x,o,64); if (lane >= o) x += t; }
    if (lane == 63) ssc[wv] = x;
    __syncthreads();
    int add = (wv>0?ssc[0]:0)+(wv>1?ssc[1]:0)+(wv>2?ssc[2]:0);
    int c = scarry;
    if (i < nb) lpre[i] = c + add + x - v;
    __syncthreads();
    if (tid == 255) scarry = c + ssc[0]+ssc[1]+ssc[2]+ssc[3];
    __syncthreads();
  }
  for (int i = tid; i < nb; i += 256) gb[i] = atomicAdd(&gcur[i], lh[i]);
  #pragma unroll
  for (int j = 0; j < 16; ++j){
    if (rk[j] >= 0){
      int bk = en[j] >> 23;
      sst[lpre[bk] + rk[j]] = en[j];
    }
  }
  __syncthreads();
  for (int j = tid; j < m; j += 256){
    unsigned e = sst[j];
    int bk = e >> 23;
    Ebuf[gb[bk] + (j - lpre[bk])] = e;
  }
}

// ---- stage 4: per-bucket CSR build, DUAL-SIDE in one launch ----
// n-side blocks additionally prescale their 256 node rows into xb0.
__global__ __launch_bounds__(256) void k_build2(
    const unsigned* __restrict__ Ebuf_h, const int* __restrict__ bstart_h,
    const unsigned* __restrict__ Ebuf_n, const int* __restrict__ bstart_n,
    int* __restrict__ off_h, float* __restrict__ is_h, int* __restrict__ csr_h,
    int* __restrict__ off_n, float* __restrict__ is_n, int* __restrict__ csr_n,
    const float* __restrict__ nf, unsigned short* __restrict__ xb,
    int Hn, int Nn){
  __shared__ int lcnt[256], lpre2[256], lcur[256];
  int tid = threadIdx.x, lane = tid & 63, wv = tid >> 6;
  bool hside = (blockIdx.x < NB_H);
  int b = hside ? blockIdx.x : blockIdx.x - NB_H;
  const unsigned* Ebuf = hside ? Ebuf_h : Ebuf_n;
  const int* bstart = hside ? bstart_h : bstart_n;
  int keyshift = hside ? 17 : 15;
  int ipb = hside ? 64 : 256;
  int paymask = hside ? 0x1FFFF : 0x7FFF;
  int limit = hside ? Hn : Nn;
  int* off = hside ? off_h : off_n;
  float* isv = hside ? is_h : is_n;
  int* csr = hside ? csr_h : csr_n;

  int base = bstart[b], m = bstart[b+1] - base;
  for (int i = tid; i < ipb; i += 256) lcnt[i] = 0;
  __syncthreads();
  for (int i = tid; i < m; i += 256){
    unsigned e = Ebuf[base + i];
    atomicAdd(&lcnt[(e >> keyshift) & (ipb-1)], 1);
  }
  __syncthreads();
  if (wv == 0){
    int carry = 0;
    for (int c = 0; c < ipb; c += 64){
      int li = c + lane;
      int v = lcnt[li]; int x = v;
      #pragma unroll
      for (int o = 1; o < 64; o <<= 1){ int t = __shfl_up(x,o,64); if (lane >= o) x += t; }
      int ex = carry + x - v;
      int id = b*ipb + li;
      if (id <= limit) off[id] = base + ex;
      if (id < limit) isv[id] = rsqrtf((float)(v > 0 ? v : 1));
      lpre2[li] = ex;
      carry += __shfl(x, 63, 64);
    }
  }
  for (int i = tid; i < ipb; i += 256) lcur[i] = 0;
  __syncthreads();
  for (int i = tid; i < m; i += 256){
    unsigned e = Ebuf[base + i];
    int li = (e >> keyshift) & (ipb-1);
    int pos = base + lpre2[li] + atomicAdd(&lcur[li], 1);
    csr[pos] = (int)(e & (unsigned)paymask);
  }
  // ---- folded prescale (n-side only): xb0 rows b*256..b*256+255 ----
  if (!hside){
    int nbase = b*256;
    for (int i = tid; i < 2048; i += 256){      // 256 rows x 8 chunks
      int li = i >> 3, kc = (i & 7)*8;
      int id = nbase + li;
      if (id < Nn){
        int v = lcnt[li];
        float s = rsqrtf((float)(v > 0 ? v : 1));
        float4 v0 = *(const float4*)&nf[(size_t)id*64 + kc];
        float4 v1 = *(const float4*)&nf[(size_t)id*64 + kc + 4];
        uint4 o;
        o.x = (unsigned)f2bf(v0.x*s) | ((unsigned)f2bf(v0.y*s) << 16);
        o.y = (unsigned)f2bf(v0.z*s) | ((unsigned)f2bf(v0.w*s) << 16);
        o.z = (unsigned)f2bf(v1.x*s) | ((unsigned)f2bf(v1.y*s) << 16);
        o.w = (unsigned)f2bf(v1.z*s) | ((unsigned)f2bf(v1.w*s) << 16);
        *(uint4*)&xb[(size_t)id*64 + kc] = o;
      }
    }
  }
}

// Convert all weights to bf16, TRANSPOSED layouts.
__global__ void k_cvtall(const float* __restrict__ W1, const float* __restrict__ W2,
                         const float* __restrict__ Wa, const float* __restrict__ Wb,
                         const float* __restrict__ Wo,
                         unsigned short* __restrict__ W1T, unsigned short* __restrict__ W2T,
                         unsigned short* __restrict__ WaT, unsigned short* __restrict__ WbT,
                         unsigned short* __restrict__ WoT){
  int st = gridDim.x*blockDim.x;
  int t0 = blockIdx.x*blockDim.x + threadIdx.x;
  for (int j = t0; j < NLAYER*16384; j += st){
    int l = j >> 14, n = (j >> 6) & 255, k = j & 63;
    W1T[j] = f2bf(W1[l*16384 + k*256 + n]);
  }
  for (int j = t0; j < NLAYER*16384; j += st){
    int l = j >> 14, o = (j >> 8) & 63, kk = j & 255;
    W2T[j] = f2bf(W2[l*16384 + kk*64 + o]);
  }
  for (int j = t0; j < NLAYER*4096; j += st){
    int l = j >> 12, n = (j >> 6) & 63, k = j & 63;
    WaT[j] = f2bf(Wa[l*4096 + k*64 + n]);
  }
  for (int j = t0; j < NLAYER*4096; j += st){
    int l = j >> 12, n = (j >> 6) & 63, k = j & 63;
    WbT[j] = f2bf(Wb[l*4096 + k*64 + n]);
  }
  for (int j = t0; j < 4096; j += st){
    int n = (j >> 6) & 63, k = j & 63;
    WoT[j] = f2bf(Wo[k*64 + n]);
  }
}

// Contiguous 16B-chunk LDS staging of a pre-transposed [rows][64] bf16 matrix (pad-72).
template<int LSTR>
static __device__ __forceinline__ void stage64(const unsigned short* __restrict__ gsrc,
    unsigned short* __restrict__ ldst, int tid, int rows){
  int nch = rows*8;
  for (int idx = tid; idx < nch; idx += 256){
    int row = idx >> 3, kc = (idx & 7)*8;
    uint4 v = *(const uint4*)&gsrc[row*64 + kc];
    *(uint4*)&ldst[row*LSTR + kc] = v;
  }
}

static __device__ __forceinline__ short8 rdswz(const unsigned short* __restrict__ l,
    int row, int slot){
  return *(const short8*)&l[(row << 6) + ((((unsigned)(slot ^ row)) & 7u) << 3)];
}

#define ACC8(u) \
  a0 += __uint_as_float(u.x << 16); a1 += __uint_as_float(u.x & 0xFFFF0000u); \
  a2 += __uint_as_float(u.y << 16); a3 += __uint_as_float(u.y & 0xFFFF0000u); \
  a4 += __uint_as_float(u.z << 16); a5 += __uint_as_float(u.z & 0xFFFF0000u); \
  a6 += __uint_as_float(u.w << 16); a7 += __uint_as_float(u.w & 0xFFFF0000u);

#define ACCV(u) \
  a[0] += __uint_as_float(u.x << 16); a[1] += __uint_as_float(u.x & 0xFFFF0000u); \
  a[2] += __uint_as_float(u.y << 16); a[3] += __uint_as_float(u.y & 0xFFFF0000u); \
  a[4] += __uint_as_float(u.z << 16); a[5] += __uint_as_float(u.z & 0xFFFF0000u); \
  a[6] += __uint_as_float(u.w << 16); a[7] += __uint_as_float(u.w & 0xFFFF0000u);

// Gather (H-side, proven): wave per row, 4x unrolled, butterfly-combine.
__global__ __launch_bounds__(256) void k_gather8(const unsigned short* __restrict__ feat,
    const int* __restrict__ csr, const int* __restrict__ off,
    unsigned short* __restrict__ agg, int nrows){
  int lane = threadIdx.x & 63, wvi = threadIdx.x >> 6;
  int g = lane >> 3;
  int ch = (lane & 7) * 8;
  int r = blockIdx.x*4 + wvi, stride = gridDim.x*4;
  for (; r < nrows; r += stride){
    int b = off[r], e = off[r+1];
    float a0=0,a1=0,a2=0,a3=0,a4=0,a5=0,a6=0,a7=0;
    int t = b;
    for (; t + 32 <= e; t += 32){
      int s0 = csr[t + g];
      int s1 = csr[t + 8 + g];
      int s2 = csr[t + 16 + g];
      int s3 = csr[t + 24 + g];
      uint4 u0 = *(const uint4*)&feat[(size_t)s0*64 + ch];
      uint4 u1 = *(const uint4*)&feat[(size_t)s1*64 + ch];
      uint4 u2 = *(const uint4*)&feat[(size_t)s2*64 + ch];
      uint4 u3 = *(const uint4*)&feat[(size_t)s3*64 + ch];
      ACC8(u0); ACC8(u1); ACC8(u2); ACC8(u3);
    }
    for (; t + 16 <= e; t += 16){
      int s0 = csr[t + g];
      int s1 = csr[t + 8 + g];
      uint4 u0 = *(const uint4*)&feat[(size_t)s0*64 + ch];
      uint4 u1 = *(const uint4*)&feat[(size_t)s1*64 + ch];
      ACC8(u0); ACC8(u1);
    }
    for (; t < e; t += 8){
      int idx = t + g;
      bool valid = idx < e;
      int s = csr[valid ? idx : b];
      uint4 u = *(const uint4*)&feat[(size_t)s*64 + ch];
      if (!valid){ u.x = 0; u.y = 0; u.z = 0; u.w = 0; }
      ACC8(u);
    }
    #pragma unroll
    for (int o = 8; o <= 32; o <<= 1){
      a0 += __shfl_xor(a0,o,64); a1 += __shfl_xor(a1,o,64);
      a2 += __shfl_xor(a2,o,64); a3 += __shfl_xor(a3,o,64);
      a4 += __shfl_xor(a4,o,64); a5 += __shfl_xor(a5,o,64);
      a6 += __shfl_xor(a6,o,64); a7 += __shfl_xor(a7,o,64);
    }
    if (g == 0){
      uint4 w;
      w.x = (unsigned)f2bf(a0) | ((unsigned)f2bf(a1) << 16);
      w.y = (unsigned)f2bf(a2) | ((unsigned)f2bf(a3) << 16);
      w.z = (unsigned)f2bf(a4) | ((unsigned)f2bf(a5) << 16);
      w.w = (unsigned)f2bf(a6) | ((unsigned)f2bf(a7) << 16);
      *(uint4*)&agg[(size_t)r*64 + ch] = w;
    }
  }
}

// Gather (N-side, r11-proven): 8 rows/wave, 8-lane group per row, serial edges,
// 2 edges in flight per group, zero cross-lane reduction.
__global__ __launch_bounds__(256) void k_gatherN(const unsigned short* __restrict__ feat,
    const int* __restrict__ csr, const int* __restrict__ off,
    unsigned short* __restrict__ agg, int nrows){
  int lane = threadIdx.x & 63, wvi = threadIdx.x >> 6;
  int g = lane >> 3;          // row slot within wave (8 rows/wave)
  int ch = (lane & 7) * 8;    // this lane's 8-column chunk
  int wid = blockIdx.x*4 + wvi;
  int nw = gridDim.x*4;
  for (int r0 = wid*8; r0 < nrows; r0 += nw*8){
    int r = r0 + g;
    bool vr = (r < nrows);
    int b = 0, e = 0;
    if (vr){ b = off[r]; e = off[r+1]; }
    float a[8] = {0,0,0,0,0,0,0,0};
    int t = b;
    for (; t + 2 <= e; t += 2){
      int s0 = csr[t];
      int s1 = csr[t+1];
      uint4 u0 = *(const uint4*)&feat[(size_t)s0*64 + ch];
      uint4 u1 = *(const uint4*)&feat[(size_t)s1*64 + ch];
      ACCV(u0); ACCV(u1);
    }
    if (t < e){
      int s = csr[t];
      uint4 u = *(const uint4*)&feat[(size_t)s*64 + ch];
      ACCV(u);
    }
    if (vr){
      uint4 w;
      w.x = (unsigned)f2bf(a[0]) | ((unsigned)f2bf(a[1]) << 16);
      w.y = (unsigned)f2bf(a[2]) | ((unsigned)f2bf(a[3]) << 16);
      w.z = (unsigned)f2bf(a[4]) | ((unsigned)f2bf(a[5]) << 16);
      w.w = (unsigned)f2bf(a[6]) | ((unsigned)f2bf(a[7]) << 16);
      *(uint4*)&agg[(size_t)r*64 + ch] = w;
    }
  }
}

// MFMA mmA (r0/r1-verified shape): 64 rows / 256-thread block, Wa staged once
// per 64 rows (4x less redundant staging + 4x fewer barriers than the 16-row
// 1-wave variant). hhsb[j] = bf16( ((aggx[j]@Wa)*is_h + ba) * is_h ).
__global__ __launch_bounds__(256) void k_mmA(const unsigned short* __restrict__ aggb,
    const unsigned short* __restrict__ WaT, const float* __restrict__ bias,
    const float* __restrict__ ihy, unsigned short* __restrict__ ouths, int nrows){
  __shared__ unsigned short sWb[64*72];
  int tid = threadIdx.x;
  int lane = tid & 63, w = tid >> 6;
  int quad = lane >> 4, n16 = lane & 15;
  stage64<72>(WaT, sWb, tid, 64);
  __syncthreads();
  int rowbase = blockIdx.x*64 + w*16;
  int arow = min(rowbase + n16, nrows-1);
  short8 a0 = *(const short8*)&aggb[(size_t)arow*64 + quad*8];
  short8 a1 = *(const short8*)&aggb[(size_t)arow*64 + 32 + quad*8];
  float ih[4];
  #pragma unroll
  for (int r = 0; r < 4; ++r) ih[r] = ihy[min(rowbase + quad*4 + r, nrows-1)];
  #pragma unroll
  for (int ot = 0; ot < 4; ++ot){
    floatx4 c = (floatx4){0.f,0.f,0.f,0.f};
    short8 b0 = *(const short8*)&sWb[(ot*16+n16)*72 + quad*8];
    short8 b1 = *(const short8*)&sWb[(ot*16+n16)*72 + 32 + quad*8];
    c = __builtin_amdgcn_mfma_f32_16x16x32_bf16(a0, b0, c, 0, 0, 0);
    c = __builtin_amdgcn_mfma_f32_16x16x32_bf16(a1, b1, c, 0, 0, 0);
    float bl = bias[ot*16 + n16];
    #pragma unroll
    for (int r = 0; r < 4; ++r){
      int rr = rowbase + quad*4 + r;
      if (rr < nrows)
        ouths[(size_t)rr*64 + ot*16 + n16] = f2bf(fmaf(c[r], ih[r], bl) * ih[r]);
    }
  }
}

// Fused per-node pipeline, STAGE-ONCE / BARRIER-FREE LOOP, 1024-thread blocks.
// FROZEN at the r9/r11-verified form: four modification attempts (r7/r8 LAST,
// r10 LAST-only, r13 software-pipeline) each failed correctness despite
// auditing as math-identical — do not modify this kernel without new
// diagnostic capability.
__global__ __launch_bounds__(1024) void k_fused(
    const unsigned short* __restrict__ aggb,
    const unsigned short* __restrict__ WbT,
    const float* __restrict__ bbg,
    const float* __restrict__ isn,
    const float* __restrict__ hin,
    const float* __restrict__ g1v, const float* __restrict__ be1v,
    const unsigned short* __restrict__ W1T, const float* __restrict__ b1g,
    const unsigned short* __restrict__ W2T, const float* __restrict__ b2g,
    const float* __restrict__ g2v, const float* __restrict__ be2v,
    float* __restrict__ Outp, unsigned short* __restrict__ Qs, int nrows)
{
  __shared__ unsigned short sWb[64*64];     // Wb (swizzled)
  __shared__ unsigned short sW1[4*64*64];   // W1, 4 quarters (swizzled)
  __shared__ unsigned short sW2[4*64*64];   // W2, 4 quarters (swizzled)
  __shared__ unsigned short sPH[16*16*72];  // per-wave scratch (P / H1 round-trips)
  int tid = threadIdx.x;
  int lane = tid & 63, w = tid >> 6;
  int quad = lane >> 4, n16 = lane & 15;
  unsigned short* myP = &sPH[w*16*72];

  // ---- stage all 9 weight tiles once (4608 16B chunks across 1024 threads) ----
  for (int c = tid; c < 4608; c += 1024){
    int tile = c >> 9, cc = c & 511;
    int row = cc >> 3, s = cc & 7;
    const unsigned short* src; unsigned short* dst; int gs;
    if (tile == 0){ src = WbT; gs = 64; dst = sWb; }
    else if (tile < 5){ int q = tile-1; src = W1T + q*64*64; gs = 64; dst = sW1 + q*4096; }
    else { int q = tile-5; src = W2T + q*64; gs = 256; dst = sW2 + q*4096; }
    uint4 v = *(const uint4*)&src[row*gs + s*8];
    *(uint4*)&dst[(row << 6) + ((((unsigned)(s ^ row)) & 7u) << 3)] = v;
  }

  // hoist per-lane constants (independent of tile)
  float bbv[4], g1l[4], be1l[4], b2v[4], g2l[4], be2l[4];
  #pragma unroll
  for (int ot = 0; ot < 4; ++ot){
    bbv[ot] = bbg[ot*16 + n16];
    g1l[ot] = g1v[ot*16 + n16];  be1l[ot] = be1v[ot*16 + n16];
    b2v[ot] = b2g[ot*16 + n16];
    g2l[ot] = g2v[ot*16 + n16];  be2l[ot] = be2v[ot*16 + n16];
  }
  float b1v[4][4];
  #pragma unroll
  for (int q = 0; q < 4; ++q)
    #pragma unroll
    for (int c2 = 0; c2 < 4; ++c2)   // c2 = ck2*2 + nt
      b1v[q][c2] = b1g[q*64 + c2*16 + n16];

  __syncthreads();   // the ONLY block barrier

  int ngrp = (nrows + 15) >> 4;
  int wwid = blockIdx.x*16 + w;
  int nw = gridDim.x*16;

  for (int grp = wwid; grp < ngrp; grp += nw){
    int rb = grp*16;

    int arow = min(rb + n16, nrows-1);
    short8 a0 = *(const short8*)&aggb[(size_t)arow*64 + quad*8];
    short8 a1 = *(const short8*)&aggb[(size_t)arow*64 + 32 + quad*8];

    float pP[4][4];
    float isr[4];
    #pragma unroll
    for (int r = 0; r < 4; ++r) isr[r] = isn[min(rb + quad*4 + r, nrows-1)];
    #pragma unroll
    for (int ot = 0; ot < 4; ++ot){
      floatx4 c = (floatx4){0.f,0.f,0.f,0.f};
      short8 b0 = rdswz(sWb, ot*16+n16, quad);
      short8 b1 = rdswz(sWb, ot*16+n16, 4+quad);
      c = __builtin_amdgcn_mfma_f32_16x16x32_bf16(a0, b0, c, 0, 0, 0);
      c = __builtin_amdgcn_mfma_f32_16x16x32_bf16(a1, b1, c, 0, 0, 0);
      #pragma unroll
      for (int r = 0; r < 4; ++r){
        int rr = min(rb + quad*4 + r, nrows-1);
        pP[ot][r] = fmaf(c[r], isr[r], bbv[ot]) + hin[(size_t)rr*64 + ot*16 + n16];
      }
    }
    // LN1
    #pragma unroll
    for (int r = 0; r < 4; ++r){
      float sv = (pP[0][r] + pP[1][r]) + (pP[2][r] + pP[3][r]);
      float q = fmaf(pP[0][r], pP[0][r], pP[1][r]*pP[1][r]) +
                fmaf(pP[2][r], pP[2][r], pP[3][r]*pP[3][r]);
      #pragma unroll
      for (int o = 8; o >= 1; o >>= 1){
        sv += __shfl_xor(sv, o, 64);
        q  += __shfl_xor(q, o, 64);
      }
      float mu = sv*(1.f/64.f);
      float var = fmaf(-mu, mu, q*(1.f/64.f));
      float rs = rsqrtf(var + 1e-5f);
      #pragma unroll
      for (int ot = 0; ot < 4; ++ot)
        pP[ot][r] = fmaf((pP[ot][r]-mu)*rs, g1l[ot], be1l[ot]);
    }
    // C-layout -> A-layout via per-wave LDS round trip (wave-private)
    #pragma unroll
    for (int ot = 0; ot < 4; ++ot)
      #pragma unroll
      for (int r = 0; r < 4; ++r)
        myP[(quad*4 + r)*72 + ot*16 + n16] = f2bf(pP[ot][r]);
    short8 p0 = *(const short8*)&myP[n16*72 + quad*8];
    short8 p1 = *(const short8*)&myP[n16*72 + 32 + quad*8];

    // FFN: all weights LDS-resident, no barriers.
    floatx4 acc2[4];
    #pragma unroll
    for (int t = 0; t < 4; ++t) acc2[t] = (floatx4){0.f,0.f,0.f,0.f};

    #pragma unroll
    for (int q = 0; q < 4; ++q){
      const unsigned short* sA = sW1 + q*4096;
      const unsigned short* sB = sW2 + q*4096;
      #pragma unroll
      for (int ck2 = 0; ck2 < 2; ++ck2){
        #pragma unroll
        for (int nt = 0; nt < 2; ++nt){
          int nl = ck2*32 + nt*16 + n16;
          floatx4 c = (floatx4){0.f,0.f,0.f,0.f};
          short8 b0 = rdswz(sA, nl, quad);
          short8 b1f = rdswz(sA, nl, 4+quad);
          c = __builtin_amdgcn_mfma_f32_16x16x32_bf16(p0, b0, c, 0, 0, 0);
          c = __builtin_amdgcn_mfma_f32_16x16x32_bf16(p1, b1f, c, 0, 0, 0);
          float bb = b1v[q][ck2*2 + nt];
          #pragma unroll
          for (int r = 0; r < 4; ++r){
            float h = fmaxf(c[r] + bb, 0.f);
            myP[(quad*4 + r)*40 + nt*16 + n16] = f2bf(h);
          }
        }
        short8 a2 = *(const short8*)&myP[n16*40 + quad*8];
        #pragma unroll
        for (int ot = 0; ot < 4; ++ot){
          short8 b2f = rdswz(sB, ot*16+n16, ck2*4 + quad);
          acc2[ot] = __builtin_amdgcn_mfma_f32_16x16x32_bf16(a2, b2f, acc2[ot], 0, 0, 0);
        }
      }
    }

    // epilogue-2 (LN2 + dual store)
    float pre[4][4];
    #pragma unroll
    for (int ot = 0; ot < 4; ++ot)
      #pragma unroll
      for (int r = 0; r < 4; ++r)
        pre[ot][r] = acc2[ot][r] + b2v[ot] + pP[ot][r];
    #pragma unroll
    for (int r = 0; r < 4; ++r){
      float sv = (pre[0][r] + pre[1][r]) + (pre[2][r] + pre[3][r]);
      float q = fmaf(pre[0][r], pre[0][r], pre[1][r]*pre[1][r]) +
                fmaf(pre[2][r], pre[2][r], pre[3][r]*pre[3][r]);
      #pragma unroll
      for (int o = 8; o >= 1; o >>= 1){
        sv += __shfl_xor(sv, o, 64);
        q  += __shfl_xor(q, o, 64);
      }
      float mu = sv*(1.f/64.f);
      float var = fmaf(-mu, mu, q*(1.f/64.f));
      float rs = rsqrtf(var + 1e-5f);
      int rr = rb + quad*4 + r;
      if (rr < nrows){
        float isr2 = isn[rr];
        #pragma unroll
        for (int ot = 0; ot < 4; ++ot){
          float ov = fmaf((pre[ot][r]-mu)*rs, g2l[ot], be2l[ot]);
          Outp[(size_t)rr*64 + ot*16 + n16] = ov;
          Qs[(size_t)rr*64 + ot*16 + n16] = f2bf(ov * isr2);
        }
      }
    }
  }
}

// MFMA final: out = LN(Q, gF, bF) @ Wo + bo
__global__ __launch_bounds__(256) void k_final(const float* __restrict__ Q,
    const unsigned short* __restrict__ WoT, const float* __restrict__ bog,
    const float* __restrict__ gF, const float* __restrict__ bF,
    float* __restrict__ out, int nrows){
  __shared__ unsigned short sWb[64*72];
  int tid = threadIdx.x;
  int lane = tid & 63, w = tid >> 6;
  int quad = lane >> 4, n16 = lane & 15;
  stage64<72>(WoT, sWb, tid, 64);
  __syncthreads();
  int rowbase = blockIdx.x*64 + w*16;
  int arow = min(rowbase + n16, nrows-1);
  float4 q0 = *(const float4*)&Q[(size_t)arow*64 + quad*8];
  float4 q1 = *(const float4*)&Q[(size_t)arow*64 + quad*8 + 4];
  float4 q2 = *(const float4*)&Q[(size_t)arow*64 + 32 + quad*8];
  float4 q3 = *(const float4*)&Q[(size_t)arow*64 + 32 + quad*8 + 4];
  float s = (q0.x+q0.y+q0.z+q0.w) + (q1.x+q1.y+q1.z+q1.w)
          + (q2.x+q2.y+q2.z+q2.w) + (q3.x+q3.y+q3.z+q3.w);
  float qq = (q0.x*q0.x+q0.y*q0.y+q0.z*q0.z+q0.w*q0.w)
           + (q1.x*q1.x+q1.y*q1.y+q1.z*q1.z+q1.w*q1.w)
           + (q2.x*q2.x+q2.y*q2.y+q2.z*q2.z+q2.w*q2.w)
           + (q3.x*q3.x+q3.y*q3.y+q3.z*q3.z+q3.w*q3.w);
  s += __shfl_xor(s, 16, 64);  qq += __shfl_xor(qq, 16, 64);
  s += __shfl_xor(s, 32, 64);  qq += __shfl_xor(qq, 32, 64);
  float mu = s*(1.f/64.f);
  float var = fmaf(-mu, mu, qq*(1.f/64.f));
  float rs = rsqrtf(var + 1e-5f);
  float4 g0 = *(const float4*)&gF[quad*8];
  float4 g1 = *(const float4*)&gF[quad*8 + 4];
  float4 g2 = *(const float4*)&gF[32 + quad*8];
  float4 g3 = *(const float4*)&gF[32 + quad*8 + 4];
  float4 f0 = *(const float4*)&bF[quad*8];
  float4 f1 = *(const float4*)&bF[quad*8 + 4];
  float4 f2 = *(const float4*)&bF[32 + quad*8];
  float4 f3 = *(const float4*)&bF[32 + quad*8 + 4];
  short8 a0, a1;
  a0[0]=f2bf(fmaf((q0.x-mu)*rs, g0.x, f0.x)); a0[1]=f2bf(fmaf((q0.y-mu)*rs, g0.y, f0.y));
  a0[2]=f2bf(fmaf((q0.z-mu)*rs, g0.z, f0.z)); a0[3]=f2bf(fmaf((q0.w-mu)*rs, g0.w, f0.w));
  a0[4]=f2bf(fmaf((q1.x-mu)*rs, g1.x, f1.x)); a0[5]=f2bf(fmaf((q1.y-mu)*rs, g1.y, f1.y));
  a0[6]=f2bf(fmaf((q1.z-mu)*rs, g1.z, f1.z)); a0[7]=f2bf(fmaf((q1.w-mu)*rs, g1.w, f1.w));
  a1[0]=f2bf(fmaf((q2.x-mu)*rs, g2.x, f2.x)); a1[1]=f2bf(fmaf((q2.y-mu)*rs, g2.y, f2.y));
  a1[2]=f2bf(fmaf((q2.z-mu)*rs, g2.z, f2.z)); a1[3]=f2bf(fmaf((q2.w-mu)*rs, g2.w, f2.w));
  a1[4]=f2bf(fmaf((q3.x-mu)*rs, g3.x, f3.x)); a1[5]=f2bf(fmaf((q3.y-mu)*rs, g3.y, f3.y));
  a1[6]=f2bf(fmaf((q3.z-mu)*rs, g3.z, f3.z)); a1[7]=f2bf(fmaf((q3.w-mu)*rs, g3.w, f3.w));
  #pragma unroll
  for (int ot = 0; ot < 4; ++ot){
    floatx4 c = (floatx4){0.f,0.f,0.f,0.f};
    short8 b0 = *(const short8*)&sWb[(ot*16+n16)*72 + quad*8];
    short8 b1 = *(const short8*)&sWb[(ot*16+n16)*72 + 32 + quad*8];
    c = __builtin_amdgcn_mfma_f32_16x16x32_bf16(a0, b0, c, 0, 0, 0);
    c = __builtin_amdgcn_mfma_f32_16x16x32_bf16(a1, b1, c, 0, 0, 0);
    float bol = bog[ot*16 + n16];
    #pragma unroll
    for (int r = 0; r < 4; ++r){
      int rr = rowbase + quad*4 + r;
      if (rr < nrows) out[(size_t)rr*64 + ot*16 + n16] = c[r] + bol;
    }
  }
}

extern "C" void kernel_launch(void* const* d_in, const int* in_sizes, int n_in,
                              void* d_out, int out_size, void* d_ws, size_t ws_size,
                              hipStream_t stream){
  const float* nf   = (const float*)d_in[0];
  const int*   esrc = (const int*)d_in[1];
  const int*   edst = (const int*)d_in[2];
  const float* Wn2h = (const float*)d_in[4];
  const float* bn2h = (const float*)d_in[5];
  const float* Wh2n = (const float*)d_in[6];
  const float* bh2n = (const float*)d_in[7];
  const float* W1   = (const float*)d_in[8];
  const float* b1   = (const float*)d_in[9];
  const float* W2   = (const float*)d_in[10];
  const float* b2   = (const float*)d_in[11];
  const float* g1   = (const float*)d_in[12];
  const float* be1  = (const float*)d_in[13];
  const float* g2   = (const float*)d_in[14];
  const float* be2  = (const float*)d_in[15];
  const float* gF   = (const float*)d_in[16];
  const float* bF   = (const float*)d_in[17];
  const float* Wo   = (const float*)d_in[18];
  const float* bo   = (const float*)d_in[19];
  const int N = in_sizes[0] / 64;
  const int E = in_sizes[1];
  const int H = HYP;
  float* out = (float*)d_out;

  char* w = (char*)d_ws;
  auto carve = [&](size_t bytes) -> char* {
    char* p = w; w += (bytes + 255) & ~(size_t)255; return p;
  };
  int* bh = (int*)carve((size_t)(NB_H + NB_N)*4);
  int* bn = bh + NB_H;
  int* bstart_h = (int*)carve((size_t)(NB_H+1)*4);
  int* gcur_h   = (int*)carve((size_t)NB_H*4);
  int* bstart_n = (int*)carve((size_t)(NB_N+1)*4);
  int* gcur_n   = (int*)carve((size_t)NB_N*4);
  unsigned* Ebuf_h = (unsigned*)carve((size_t)E*4);
  unsigned* Ebuf_n = (unsigned*)carve((size_t)E*4);
  int*   off_h = (int*)carve((size_t)(H+1)*4);
  int*   off_n = (int*)carve((size_t)(N+1)*4);
  float* is_h  = (float*)carve((size_t)H*4);
  float* is_n  = (float*)carve((size_t)N*4);
  int*   csr_h = (int*)carve((size_t)E*4);
  int*   csr_n = (int*)carve((size_t)E*4);
  unsigned short* aggxb = (unsigned short*)carve((size_t)H*64*2);
  unsigned short* agghb = (unsigned short*)carve((size_t)N*64*2);
  float* Qb    = (float*)carve((size_t)N*64*4);
  unsigned short* hhsb = (unsigned short*)carve((size_t)H*64*2);
  unsigned short* xb0  = (unsigned short*)carve((size_t)N*64*2);
  unsigned short* Qs   = (unsigned short*)carve((size_t)N*64*2);
  unsigned short* W1g16 = (unsigned short*)carve((size_t)NLAYER*64*256*2);
  unsigned short* W2g16 = (unsigned short*)carve((size_t)NLAYER*256*64*2);
  unsigned short* Wag16 = (unsigned short*)carve((size_t)NLAYER*4096*2);
  unsigned short* Wbg16 = (unsigned short*)carve((size_t)NLAYER*4096*2);
  unsigned short* Wog16 = (unsigned short*)carve((size_t)4096*2);

  hipMemsetAsync(bh, 0, (size_t)(NB_H + NB_N)*4, stream);
  k_cvtall<<<96, 256, 0, stream>>>(W1, W2, Wn2h, Wh2n, Wo,
                                   W1g16, W2g16, Wag16, Wbg16, Wog16);
  k_hist<<<512, 256, 0, stream>>>(esrc, edst, E, bh, bn);
  k_bscan<<<1, 256, 0, stream>>>(bh, bn, bstart_h, gcur_h, bstart_n, gcur_n);
  const int nblk = (E + PT - 1)/PT;
  k_partition2<<<2*nblk, 256, 0, stream>>>(esrc, edst, E, nblk,
                                           gcur_h, Ebuf_h, gcur_n, Ebuf_n);
  k_build2<<<NB_H + NB_N, 256, 0, stream>>>(Ebuf_h, bstart_h, Ebuf_n, bstart_n,
                                            off_h, is_h, csr_h,
                                            off_n, is_n, csr_n,
                                            nf, xb0, H, N);

  const int NB64 = (N + 63)/64;
  const int HB64 = (H + 63)/64;
  for (int l = 0; l < NLAYER; ++l){
    const float* hin = (l == 0) ? nf : Qb;
    const unsigned short* hsrc = (l == 0) ? xb0 : Qs;
    k_gather8<<<2048, 256, 0, stream>>>(hsrc, csr_h, off_h, aggxb, H);
    k_mmA<<<HB64, 256, 0, stream>>>(aggxb, Wag16 + l*4096, bn2h + l*64, is_h, hhsb, H);
    k_gatherN<<<2048, 256, 0, stream>>>(hhsb, csr_n, off_n, agghb, N);
    k_fused<<<256, 1024, 0, stream>>>(agghb, Wbg16 + l*4096, bh2n + l*64, is_n, hin,
                                      g1 + l*64, be1 + l*64,
                                      W1g16 + l*64*256, b1 + l*256,
                                      W2g16 + l*256*64, b2 + l*64,
                                      g2 + l*64, be2 + l*64, Qb, Qs, N);
  }
  k_final<<<NB64, 256, 0, stream>>>(Qb, Wog16, bo, gF, bF, out, N);
}

// Round 15
// 444.294 us; speedup vs baseline: 1.2433x; 1.0140x over previous
//
#include <hip/hip_runtime.h>

// Problem constants (from reference): N=100000, H=20000, E=1600000, D=64, L=3, F=256
#define HYP 20000
#define NLAYER 3
// Bucket-sort geometry: ids fit 15 bits (H=20000) / 17 bits (N=100000).
#define NB_H 313
#define NB_N 391
#define PT 4096

typedef __attribute__((ext_vector_type(8))) short short8;
typedef __attribute__((ext_vector_type(4))) float floatx4;

static __device__ __forceinline__ unsigned short f2bf(float f){
  union { float f; unsigned u; } v; v.f = f;
  unsigned r = v.u + 0x7FFF + ((v.u >> 16) & 1);
  return (unsigned short)(r >> 16);
}

// ---- CSR build, stage 1: global bucket histogram (LDS-staged) ----
__global__ __launch_bounds__(256) void k_hist(const int* __restrict__ src,
    const int* __restrict__ dst, int E, int* __restrict__ bh, int* __restrict__ bn){
  __shared__ int lh[NB_H + NB_N];
  int tid = threadIdx.x;
  for (int i = tid; i < NB_H + NB_N; i += 256) lh[i] = 0;
  __syncthreads();
  for (int i = blockIdx.x*256 + tid; i < E; i += gridDim.x*256){
    atomicAdd(&lh[dst[i] >> 6], 1);
    atomicAdd(&lh[NB_H + (src[i] >> 8)], 1);
  }
  __syncthreads();
  for (int i = tid; i < NB_H; i += 256) if (lh[i]) atomicAdd(&bh[i], lh[i]);
  for (int i = tid; i < NB_N; i += 256) if (lh[NB_H+i]) atomicAdd(&bn[i], lh[NB_H+i]);
}

// ---- stage 2: exclusive scan of bucket counts -> bucket starts + cursors ----
__global__ __launch_bounds__(256) void k_bscan(const int* __restrict__ bh,
    const int* __restrict__ bn, int* __restrict__ bstart_h, int* __restrict__ gcur_h,
    int* __restrict__ bstart_n, int* __restrict__ gcur_n){
  __shared__ int ssc[4];
  __shared__ int scarry;
  int tid = threadIdx.x, lane = tid & 63, wv = tid >> 6;
  if (tid == 0) scarry = 0;
  __syncthreads();
  for (int base = 0; base < NB_H; base += 256){
    int i = base + tid; int v = (i < NB_H) ? bh[i] : 0; int x = v;
    #pragma unroll
    for (int o = 1; o < 64; o <<= 1){ int t = __shfl_up(x,o,64); if (lane >= o) x += t; }
    if (lane == 63) ssc[wv] = x;
    __syncthreads();
    int add = (wv>0?ssc[0]:0)+(wv>1?ssc[1]:0)+(wv>2?ssc[2]:0);
    int c = scarry;
    if (i < NB_H){ int ex = c + add + x - v; bstart_h[i] = ex; gcur_h[i] = ex; }
    __syncthreads();
    if (tid == 255) scarry = c + ssc[0]+ssc[1]+ssc[2]+ssc[3];
    __syncthreads();
  }
  if (tid == 0){ bstart_h[NB_H] = scarry; scarry = 0; }
  __syncthreads();
  for (int base = 0; base < NB_N; base += 256){
    int i = base + tid; int v = (i < NB_N) ? bn[i] : 0; int x = v;
    #pragma unroll
    for (int o = 1; o < 64; o <<= 1){ int t = __shfl_up(x,o,64); if (lane >= o) x += t; }
    if (lane == 63) ssc[wv] = x;
    __syncthreads();
    int add = (wv>0?ssc[0]:0)+(wv>1?ssc[1]:0)+(wv>2?ssc[2]:0);
    int c = scarry;
    if (i < NB_N){ int ex = c + add + x - v; bstart_n[i] = ex; gcur_n[i] = ex; }
    __syncthreads();
    if (tid == 255) scarry = c + ssc[0]+ssc[1]+ssc[2]+ssc[3];
    __syncthreads();
  }
  if (tid == 0) bstart_n[NB_N] = scarry;
}

// ---- stage 3: LDS-staged radix partition, DUAL-SIDE in one launch ----
__global__ __launch_bounds__(256) void k_partition2(
    const int* __restrict__ esrc, const int* __restrict__ edst, int E, int nblk,
    int* __restrict__ gcur_h, unsigned* __restrict__ Ebuf_h,
    int* __restrict__ gcur_n, unsigned* __restrict__ Ebuf_n){
  __shared__ unsigned sst[PT];
  __shared__ int lh[NB_N], lpre[NB_N], gb[NB_N];
  __shared__ int ssc[4];
  __shared__ int scarry;
  int tid = threadIdx.x, lane = tid & 63, wv = tid >> 6;
  bool hside = (blockIdx.x < nblk);
  int bb = hside ? blockIdx.x : blockIdx.x - nblk;
  const int* keys = hside ? edst : esrc;
  const int* pays = hside ? esrc : edst;
  int keyshift = hside ? 17 : 15;
  int nb = hside ? NB_H : NB_N;
  int* gcur = hside ? gcur_h : gcur_n;
  unsigned* Ebuf = hside ? Ebuf_h : Ebuf_n;

  int base = bb*PT;
  int m = min(PT, E - base);
  for (int i = tid; i < nb; i += 256) lh[i] = 0;
  if (tid == 0) scarry = 0;
  __syncthreads();
  unsigned en[16]; int rk[16];
  #pragma unroll
  for (int j = 0; j < 16; ++j){
    int i = base + j*256 + tid;
    if (i < E){
      unsigned k = (unsigned)keys[i], p = (unsigned)pays[i];
      en[j] = (k << keyshift) | p;
      rk[j] = atomicAdd(&lh[en[j] >> 23], 1);
    } else { en[j] = 0; rk[j] = -1; }
  }
  __syncthreads();
  for (int b2 = 0; b2 < nb; b2 += 256){
    int i = b2 + tid; int v = (i < nb) ? lh[i] : 0; int x = v;
    #pragma unroll
    for (int o = 1; o < 64; o <<= 1){ int t = __shfl_up(x,o,64); if (lane >= o) x += t; }
    if (lane == 63) ssc[wv] = x;
    __syncthreads();
    int add = (wv>0?ssc[0]:0)+(wv>1?ssc[1]:0)+(wv>2?ssc[2]:0);
    int c = scarry;
    if (i < nb) lpre[i] = c + add + x - v;
    __syncthreads();
    if (tid == 255) scarry = c + ssc[0]+ssc[1]+ssc[2]+ssc[3];
    __syncthreads();
  }
  for (int i = tid; i < nb; i += 256) gb[i] = atomicAdd(&gcur[i], lh[i]);
  #pragma unroll
  for (int j = 0; j < 16; ++j){
    if (rk[j] >= 0){
      int bk = en[j] >> 23;
      sst[lpre[bk] + rk[j]] = en[j];
    }
  }
  __syncthreads();
  for (int j = tid; j < m; j += 256){
    unsigned e = sst[j];
    int bk = e >> 23;
    Ebuf[gb[bk] + (j - lpre[bk])] = e;
  }
}

// ---- stage 4: per-bucket CSR build, DUAL-SIDE in one launch ----
// n-side blocks additionally prescale their 256 node rows into xb0.
__global__ __launch_bounds__(256) void k_build2(
    const unsigned* __restrict__ Ebuf_h, const int* __restrict__ bstart_h,
    const unsigned* __restrict__ Ebuf_n, const int* __restrict__ bstart_n,
    int* __restrict__ off_h, float* __restrict__ is_h, int* __restrict__ csr_h,
    int* __restrict__ off_n, float* __restrict__ is_n, int* __restrict__ csr_n,
    const float* __restrict__ nf, unsigned short* __restrict__ xb,
    int Hn, int Nn){
  __shared__ int lcnt[256], lpre2[256], lcur[256];
  int tid = threadIdx.x, lane = tid & 63, wv = tid >> 6;
  bool hside = (blockIdx.x < NB_H);
  int b = hside ? blockIdx.x : blockIdx.x - NB_H;
  const unsigned* Ebuf = hside ? Ebuf_h : Ebuf_n;
  const int* bstart = hside ? bstart_h : bstart_n;
  int keyshift = hside ? 17 : 15;
  int ipb = hside ? 64 : 256;
  int paymask = hside ? 0x1FFFF : 0x7FFF;
  int limit = hside ? Hn : Nn;
  int* off = hside ? off_h : off_n;
  float* isv = hside ? is_h : is_n;
  int* csr = hside ? csr_h : csr_n;

  int base = bstart[b], m = bstart[b+1] - base;
  for (int i = tid; i < ipb; i += 256) lcnt[i] = 0;
  __syncthreads();
  for (int i = tid; i < m; i += 256){
    unsigned e = Ebuf[base + i];
    atomicAdd(&lcnt[(e >> keyshift) & (ipb-1)], 1);
  }
  __syncthreads();
  if (wv == 0){
    int carry = 0;
    for (int c = 0; c < ipb; c += 64){
      int li = c + lane;
      int v = lcnt[li]; int x = v;
      #pragma unroll
      for (int o = 1; o < 64; o <<= 1){ int t = __shfl_up(x,o,64); if (lane >= o) x += t; }
      int ex = carry + x - v;
      int id = b*ipb + li;
      if (id <= limit) off[id] = base + ex;
      if (id < limit) isv[id] = rsqrtf((float)(v > 0 ? v : 1));
      lpre2[li] = ex;
      carry += __shfl(x, 63, 64);
    }
  }
  for (int i = tid; i < ipb; i += 256) lcur[i] = 0;
  __syncthreads();
  for (int i = tid; i < m; i += 256){
    unsigned e = Ebuf[base + i];
    int li = (e >> keyshift) & (ipb-1);
    int pos = base + lpre2[li] + atomicAdd(&lcur[li], 1);
    csr[pos] = (int)(e & (unsigned)paymask);
  }
  // ---- folded prescale (n-side only): xb0 rows b*256..b*256+255 ----
  if (!hside){
    int nbase = b*256;
    for (int i = tid; i < 2048; i += 256){      // 256 rows x 8 chunks
      int li = i >> 3, kc = (i & 7)*8;
      int id = nbase + li;
      if (id < Nn){
        int v = lcnt[li];
        float s = rsqrtf((float)(v > 0 ? v : 1));
        float4 v0 = *(const float4*)&nf[(size_t)id*64 + kc];
        float4 v1 = *(const float4*)&nf[(size_t)id*64 + kc + 4];
        uint4 o;
        o.x = (unsigned)f2bf(v0.x*s) | ((unsigned)f2bf(v0.y*s) << 16);
        o.y = (unsigned)f2bf(v0.z*s) | ((unsigned)f2bf(v0.w*s) << 16);
        o.z = (unsigned)f2bf(v1.x*s) | ((unsigned)f2bf(v1.y*s) << 16);
        o.w = (unsigned)f2bf(v1.z*s) | ((unsigned)f2bf(v1.w*s) << 16);
        *(uint4*)&xb[(size_t)id*64 + kc] = o;
      }
    }
  }
}

// Convert all weights to bf16, TRANSPOSED layouts.
__global__ void k_cvtall(const float* __restrict__ W1, const float* __restrict__ W2,
                         const float* __restrict__ Wa, const float* __restrict__ Wb,
                         const float* __restrict__ Wo,
                         unsigned short* __restrict__ W1T, unsigned short* __restrict__ W2T,
                         unsigned short* __restrict__ WaT, unsigned short* __restrict__ WbT,
                         unsigned short* __restrict__ WoT){
  int st = gridDim.x*blockDim.x;
  int t0 = blockIdx.x*blockDim.x + threadIdx.x;
  for (int j = t0; j < NLAYER*16384; j += st){
    int l = j >> 14, n = (j >> 6) & 255, k = j & 63;
    W1T[j] = f2bf(W1[l*16384 + k*256 + n]);
  }
  for (int j = t0; j < NLAYER*16384; j += st){
    int l = j >> 14, o = (j >> 8) & 63, kk = j & 255;
    W2T[j] = f2bf(W2[l*16384 + kk*64 + o]);
  }
  for (int j = t0; j < NLAYER*4096; j += st){
    int l = j >> 12, n = (j >> 6) & 63, k = j & 63;
    WaT[j] = f2bf(Wa[l*4096 + k*64 + n]);
  }
  for (int j = t0; j < NLAYER*4096; j += st){
    int l = j >> 12, n = (j >> 6) & 63, k = j & 63;
    WbT[j] = f2bf(Wb[l*4096 + k*64 + n]);
  }
  for (int j = t0; j < 4096; j += st){
    int n = (j >> 6) & 63, k = j & 63;
    WoT[j] = f2bf(Wo[k*64 + n]);
  }
}

// Contiguous 16B-chunk LDS staging of a pre-transposed [rows][64] bf16 matrix (pad-72).
template<int LSTR>
static __device__ __forceinline__ void stage64(const unsigned short* __restrict__ gsrc,
    unsigned short* __restrict__ ldst, int tid, int rows){
  int nch = rows*8;
  for (int idx = tid; idx < nch; idx += 256){
    int row = idx >> 3, kc = (idx & 7)*8;
    uint4 v = *(const uint4*)&gsrc[row*64 + kc];
    *(uint4*)&ldst[row*LSTR + kc] = v;
  }
}

static __device__ __forceinline__ short8 rdswz(const unsigned short* __restrict__ l,
    int row, int slot){
  return *(const short8*)&l[(row << 6) + ((((unsigned)(slot ^ row)) & 7u) << 3)];
}

#define ACC8(u) \
  a0 += __uint_as_float(u.x << 16); a1 += __uint_as_float(u.x & 0xFFFF0000u); \
  a2 += __uint_as_float(u.y << 16); a3 += __uint_as_float(u.y & 0xFFFF0000u); \
  a4 += __uint_as_float(u.z << 16); a5 += __uint_as_float(u.z & 0xFFFF0000u); \
  a6 += __uint_as_float(u.w << 16); a7 += __uint_as_float(u.w & 0xFFFF0000u);

#define ACCV(u) \
  a[0] += __uint_as_float(u.x << 16); a[1] += __uint_as_float(u.x & 0xFFFF0000u); \
  a[2] += __uint_as_float(u.y << 16); a[3] += __uint_as_float(u.y & 0xFFFF0000u); \
  a[4] += __uint_as_float(u.z << 16); a[5] += __uint_as_float(u.z & 0xFFFF0000u); \
  a[6] += __uint_as_float(u.w << 16); a[7] += __uint_as_float(u.w & 0xFFFF0000u);

// Gather (H-side, deg~80): wave per row; NEW leading 64-edge loop with 8 loads
// in flight (one burst covers most of a row), then the proven 32/16/8 ladder.
// Per-lane accumulation order is unchanged (same slot sequence) => bit-identical.
__global__ __launch_bounds__(256) void k_gather8(const unsigned short* __restrict__ feat,
    const int* __restrict__ csr, const int* __restrict__ off,
    unsigned short* __restrict__ agg, int nrows){
  int lane = threadIdx.x & 63, wvi = threadIdx.x >> 6;
  int g = lane >> 3;
  int ch = (lane & 7) * 8;
  int r = blockIdx.x*4 + wvi, stride = gridDim.x*4;
  for (; r < nrows; r += stride){
    int b = off[r], e = off[r+1];
    float a0=0,a1=0,a2=0,a3=0,a4=0,a5=0,a6=0,a7=0;
    int t = b;
    for (; t + 64 <= e; t += 64){
      int s0 = csr[t + g];
      int s1 = csr[t + 8 + g];
      int s2 = csr[t + 16 + g];
      int s3 = csr[t + 24 + g];
      int s4 = csr[t + 32 + g];
      int s5 = csr[t + 40 + g];
      int s6 = csr[t + 48 + g];
      int s7 = csr[t + 56 + g];
      uint4 u0 = *(const uint4*)&feat[(size_t)s0*64 + ch];
      uint4 u1 = *(const uint4*)&feat[(size_t)s1*64 + ch];
      uint4 u2 = *(const uint4*)&feat[(size_t)s2*64 + ch];
      uint4 u3 = *(const uint4*)&feat[(size_t)s3*64 + ch];
      uint4 u4 = *(const uint4*)&feat[(size_t)s4*64 + ch];
      uint4 u5 = *(const uint4*)&feat[(size_t)s5*64 + ch];
      uint4 u6 = *(const uint4*)&feat[(size_t)s6*64 + ch];
      uint4 u7 = *(const uint4*)&feat[(size_t)s7*64 + ch];
      ACC8(u0); ACC8(u1); ACC8(u2); ACC8(u3);
      ACC8(u4); ACC8(u5); ACC8(u6); ACC8(u7);
    }
    for (; t + 32 <= e; t += 32){
      int s0 = csr[t + g];
      int s1 = csr[t + 8 + g];
      int s2 = csr[t + 16 + g];
      int s3 = csr[t + 24 + g];
      uint4 u0 = *(const uint4*)&feat[(size_t)s0*64 + ch];
      uint4 u1 = *(const uint4*)&feat[(size_t)s1*64 + ch];
      uint4 u2 = *(const uint4*)&feat[(size_t)s2*64 + ch];
      uint4 u3 = *(const uint4*)&feat[(size_t)s3*64 + ch];
      ACC8(u0); ACC8(u1); ACC8(u2); ACC8(u3);
    }
    for (; t + 16 <= e; t += 16){
      int s0 = csr[t + g];
      int s1 = csr[t + 8 + g];
      uint4 u0 = *(const uint4*)&feat[(size_t)s0*64 + ch];
      uint4 u1 = *(const uint4*)&feat[(size_t)s1*64 + ch];
      ACC8(u0); ACC8(u1);
    }
    for (; t < e; t += 8){
      int idx = t + g;
      bool valid = idx < e;
      int s = csr[valid ? idx : b];
      uint4 u = *(const uint4*)&feat[(size_t)s*64 + ch];
      if (!valid){ u.x = 0; u.y = 0; u.z = 0; u.w = 0; }
      ACC8(u);
    }
    #pragma unroll
    for (int o = 8; o <= 32; o <<= 1){
      a0 += __shfl_xor(a0,o,64); a1 += __shfl_xor(a1,o,64);
      a2 += __shfl_xor(a2,o,64); a3 += __shfl_xor(a3,o,64);
      a4 += __shfl_xor(a4,o,64); a5 += __shfl_xor(a5,o,64);
      a6 += __shfl_xor(a6,o,64); a7 += __shfl_xor(a7,o,64);
    }
    if (g == 0){
      uint4 w;
      w.x = (unsigned)f2bf(a0) | ((unsigned)f2bf(a1) << 16);
      w.y = (unsigned)f2bf(a2) | ((unsigned)f2bf(a3) << 16);
      w.z = (unsigned)f2bf(a4) | ((unsigned)f2bf(a5) << 16);
      w.w = (unsigned)f2bf(a6) | ((unsigned)f2bf(a7) << 16);
      *(uint4*)&agg[(size_t)r*64 + ch] = w;
    }
  }
}

// Gather (N-side, deg~16): 8 rows/wave, 8-lane group per row, zero cross-lane
// reduction. NEW leading 4-edge loop (4 loads in flight; ~halves exposed-latency
// events per row vs the 2-edge loop), then 2-edge and 1-edge tails. Per-lane
// accumulation order unchanged => bit-identical.
__global__ __launch_bounds__(256) void k_gatherN(const unsigned short* __restrict__ feat,
    const int* __restrict__ csr, const int* __restrict__ off,
    unsigned short* __restrict__ agg, int nrows){
  int lane = threadIdx.x & 63, wvi = threadIdx.x >> 6;
  int g = lane >> 3;          // row slot within wave (8 rows/wave)
  int ch = (lane & 7) * 8;    // this lane's 8-column chunk
  int wid = blockIdx.x*4 + wvi;
  int nw = gridDim.x*4;
  for (int r0 = wid*8; r0 < nrows; r0 += nw*8){
    int r = r0 + g;
    bool vr = (r < nrows);
    int b = 0, e = 0;
    if (vr){ b = off[r]; e = off[r+1]; }
    float a[8] = {0,0,0,0,0,0,0,0};
    int t = b;
    for (; t + 4 <= e; t += 4){
      int s0 = csr[t];
      int s1 = csr[t+1];
      int s2 = csr[t+2];
      int s3 = csr[t+3];
      uint4 u0 = *(const uint4*)&feat[(size_t)s0*64 + ch];
      uint4 u1 = *(const uint4*)&feat[(size_t)s1*64 + ch];
      uint4 u2 = *(const uint4*)&feat[(size_t)s2*64 + ch];
      uint4 u3 = *(const uint4*)&feat[(size_t)s3*64 + ch];
      ACCV(u0); ACCV(u1); ACCV(u2); ACCV(u3);
    }
    for (; t + 2 <= e; t += 2){
      int s0 = csr[t];
      int s1 = csr[t+1];
      uint4 u0 = *(const uint4*)&feat[(size_t)s0*64 + ch];
      uint4 u1 = *(const uint4*)&feat[(size_t)s1*64 + ch];
      ACCV(u0); ACCV(u1);
    }
    if (t < e){
      int s = csr[t];
      uint4 u = *(const uint4*)&feat[(size_t)s*64 + ch];
      ACCV(u);
    }
    if (vr){
      uint4 w;
      w.x = (unsigned)f2bf(a[0]) | ((unsigned)f2bf(a[1]) << 16);
      w.y = (unsigned)f2bf(a[2]) | ((unsigned)f2bf(a[3]) << 16);
      w.z = (unsigned)f2bf(a[4]) | ((unsigned)f2bf(a[5]) << 16);
      w.w = (unsigned)f2bf(a[6]) | ((unsigned)f2bf(a[7]) << 16);
      *(uint4*)&agg[(size_t)r*64 + ch] = w;
    }
  }
}

// MFMA mmA (r0/r1-verified shape): 64 rows / 256-thread block, Wa staged once.
__global__ __launch_bounds__(256) void k_mmA(const unsigned short* __restrict__ aggb,
    const unsigned short* __restrict__ WaT, const float* __restrict__ bias,
    const float* __restrict__ ihy, unsigned short* __restrict__ ouths, int nrows){
  __shared__ unsigned short sWb[64*72];
  int tid = threadIdx.x;
  int lane = tid & 63, w = tid >> 6;
  int quad = lane >> 4, n16 = lane & 15;
  stage64<72>(WaT, sWb, tid, 64);
  __syncthreads();
  int rowbase = blockIdx.x*64 + w*16;
  int arow = min(rowbase + n16, nrows-1);
  short8 a0 = *(const short8*)&aggb[(size_t)arow*64 + quad*8];
  short8 a1 = *(const short8*)&aggb[(size_t)arow*64 + 32 + quad*8];
  float ih[4];
  #pragma unroll
  for (int r = 0; r < 4; ++r) ih[r] = ihy[min(rowbase + quad*4 + r, nrows-1)];
  #pragma unroll
  for (int ot = 0; ot < 4; ++ot){
    floatx4 c = (floatx4){0.f,0.f,0.f,0.f};
    short8 b0 = *(const short8*)&sWb[(ot*16+n16)*72 + quad*8];
    short8 b1 = *(const short8*)&sWb[(ot*16+n16)*72 + 32 + quad*8];
    c = __builtin_amdgcn_mfma_f32_16x16x32_bf16(a0, b0, c, 0, 0, 0);
    c = __builtin_amdgcn_mfma_f32_16x16x32_bf16(a1, b1, c, 0, 0, 0);
    float bl = bias[ot*16 + n16];
    #pragma unroll
    for (int r = 0; r < 4; ++r){
      int rr = rowbase + quad*4 + r;
      if (rr < nrows)
        ouths[(size_t)rr*64 + ot*16 + n16] = f2bf(fmaf(c[r], ih[r], bl) * ih[r]);
    }
  }
}

// Fused per-node pipeline, STAGE-ONCE / BARRIER-FREE LOOP, 1024-thread blocks.
// FROZEN at the r9/r11/r14-verified form (4 modification attempts failed).
__global__ __launch_bounds__(1024) void k_fused(
    const unsigned short* __restrict__ aggb,
    const unsigned short* __restrict__ WbT,
    const float* __restrict__ bbg,
    const float* __restrict__ isn,
    const float* __restrict__ hin,
    const float* __restrict__ g1v, const float* __restrict__ be1v,
    const unsigned short* __restrict__ W1T, const float* __restrict__ b1g,
    const unsigned short* __restrict__ W2T, const float* __restrict__ b2g,
    const float* __restrict__ g2v, const float* __restrict__ be2v,
    float* __restrict__ Outp, unsigned short* __restrict__ Qs, int nrows)
{
  __shared__ unsigned short sWb[64*64];     // Wb (swizzled)
  __shared__ unsigned short sW1[4*64*64];   // W1, 4 quarters (swizzled)
  __shared__ unsigned short sW2[4*64*64];   // W2, 4 quarters (swizzled)
  __shared__ unsigned short sPH[16*16*72];  // per-wave scratch (P / H1 round-trips)
  int tid = threadIdx.x;
  int lane = tid & 63, w = tid >> 6;
  int quad = lane >> 4, n16 = lane & 15;
  unsigned short* myP = &sPH[w*16*72];

  // ---- stage all 9 weight tiles once (4608 16B chunks across 1024 threads) ----
  for (int c = tid; c < 4608; c += 1024){
    int tile = c >> 9, cc = c & 511;
    int row = cc >> 3, s = cc & 7;
    const unsigned short* src; unsigned short* dst; int gs;
    if (tile == 0){ src = WbT; gs = 64; dst = sWb; }
    else if (tile < 5){ int q = tile-1; src = W1T + q*64*64; gs = 64; dst = sW1 + q*4096; }
    else { int q = tile-5; src = W2T + q*64; gs = 256; dst = sW2 + q*4096; }
    uint4 v = *(const uint4*)&src[row*gs + s*8];
    *(uint4*)&dst[(row << 6) + ((((unsigned)(s ^ row)) & 7u) << 3)] = v;
  }

  // hoist per-lane constants (independent of tile)
  float bbv[4], g1l[4], be1l[4], b2v[4], g2l[4], be2l[4];
  #pragma unroll
  for (int ot = 0; ot < 4; ++ot){
    bbv[ot] = bbg[ot*16 + n16];
    g1l[ot] = g1v[ot*16 + n16];  be1l[ot] = be1v[ot*16 + n16];
    b2v[ot] = b2g[ot*16 + n16];
    g2l[ot] = g2v[ot*16 + n16];  be2l[ot] = be2v[ot*16 + n16];
  }
  float b1v[4][4];
  #pragma unroll
  for (int q = 0; q < 4; ++q)
    #pragma unroll
    for (int c2 = 0; c2 < 4; ++c2)   // c2 = ck2*2 + nt
      b1v[q][c2] = b1g[q*64 + c2*16 + n16];

  __syncthreads();   // the ONLY block barrier

  int ngrp = (nrows + 15) >> 4;
  int wwid = blockIdx.x*16 + w;
  int nw = gridDim.x*16;

  for (int grp = wwid; grp < ngrp; grp += nw){
    int rb = grp*16;

    int arow = min(rb + n16, nrows-1);
    short8 a0 = *(const short8*)&aggb[(size_t)arow*64 + quad*8];
    short8 a1 = *(const short8*)&aggb[(size_t)arow*64 + 32 + quad*8];

    float pP[4][4];
    float isr[4];
    #pragma unroll
    for (int r = 0; r < 4; ++r) isr[r] = isn[min(rb + quad*4 + r, nrows-1)];
    #pragma unroll
    for (int ot = 0; ot < 4; ++ot){
      floatx4 c = (floatx4){0.f,0.f,0.f,0.f};
      short8 b0 = rdswz(sWb, ot*16+n16, quad);
      short8 b1 = rdswz(sWb, ot*16+n16, 4+quad);
      c = __builtin_amdgcn_mfma_f32_16x16x32_bf16(a0, b0, c, 0, 0, 0);
      c = __builtin_amdgcn_mfma_f32_16x16x32_bf16(a1, b1, c, 0, 0, 0);
      #pragma unroll
      for (int r = 0; r < 4; ++r){
        int rr = min(rb + quad*4 + r, nrows-1);
        pP[ot][r] = fmaf(c[r], isr[r], bbv[ot]) + hin[(size_t)rr*64 + ot*16 + n16];
      }
    }
    // LN1
    #pragma unroll
    for (int r = 0; r < 4; ++r){
      float sv = (pP[0][r] + pP[1][r]) + (pP[2][r] + pP[3][r]);
      float q = fmaf(pP[0][r], pP[0][r], pP[1][r]*pP[1][r]) +
                fmaf(pP[2][r], pP[2][r], pP[3][r]*pP[3][r]);
      #pragma unroll
      for (int o = 8; o >= 1; o >>= 1){
        sv += __shfl_xor(sv, o, 64);
        q  += __shfl_xor(q, o, 64);
      }
      float mu = sv*(1.f/64.f);
      float var = fmaf(-mu, mu, q*(1.f/64.f));
      float rs = rsqrtf(var + 1e-5f);
      #pragma unroll
      for (int ot = 0; ot < 4; ++ot)
        pP[ot][r] = fmaf((pP[ot][r]-mu)*rs, g1l[ot], be1l[ot]);
    }
    // C-layout -> A-layout via per-wave LDS round trip (wave-private)
    #pragma unroll
    for (int ot = 0; ot < 4; ++ot)
      #pragma unroll
      for (int r = 0; r < 4; ++r)
        myP[(quad*4 + r)*72 + ot*16 + n16] = f2bf(pP[ot][r]);
    short8 p0 = *(const short8*)&myP[n16*72 + quad*8];
    short8 p1 = *(const short8*)&myP[n16*72 + 32 + quad*8];

    // FFN: all weights LDS-resident, no barriers.
    floatx4 acc2[4];
    #pragma unroll
    for (int t = 0; t < 4; ++t) acc2[t] = (floatx4){0.f,0.f,0.f,0.f};

    #pragma unroll
    for (int q = 0; q < 4; ++q){
      const unsigned short* sA = sW1 + q*4096;
      const unsigned short* sB = sW2 + q*4096;
      #pragma unroll
      for (int ck2 = 0; ck2 < 2; ++ck2){
        #pragma unroll
        for (int nt = 0; nt < 2; ++nt){
          int nl = ck2*32 + nt*16 + n16;
          floatx4 c = (floatx4){0.f,0.f,0.f,0.f};
          short8 b0 = rdswz(sA, nl, quad);
          short8 b1f = rdswz(sA, nl, 4+quad);
          c = __builtin_amdgcn_mfma_f32_16x16x32_bf16(p0, b0, c, 0, 0, 0);
          c = __builtin_amdgcn_mfma_f32_16x16x32_bf16(p1, b1f, c, 0, 0, 0);
          float bb = b1v[q][ck2*2 + nt];
          #pragma unroll
          for (int r = 0; r < 4; ++r){
            float h = fmaxf(c[r] + bb, 0.f);
            myP[(quad*4 + r)*40 + nt*16 + n16] = f2bf(h);
          }
        }
        short8 a2 = *(const short8*)&myP[n16*40 + quad*8];
        #pragma unroll
        for (int ot = 0; ot < 4; ++ot){
          short8 b2f = rdswz(sB, ot*16+n16, ck2*4 + quad);
          acc2[ot] = __builtin_amdgcn_mfma_f32_16x16x32_bf16(a2, b2f, acc2[ot], 0, 0, 0);
        }
      }
    }

    // epilogue-2 (LN2 + dual store)
    float pre[4][4];
    #pragma unroll
    for (int ot = 0; ot < 4; ++ot)
      #pragma unroll
      for (int r = 0; r < 4; ++r)
        pre[ot][r] = acc2[ot][r] + b2v[ot] + pP[ot][r];
    #pragma unroll
    for (int r = 0; r < 4; ++r){
      float sv = (pre[0][r] + pre[1][r]) + (pre[2][r] + pre[3][r]);
      float q = fmaf(pre[0][r], pre[0][r], pre[1][r]*pre[1][r]) +
                fmaf(pre[2][r], pre[2][r], pre[3][r]*pre[3][r]);
      #pragma unroll
      for (int o = 8; o >= 1; o >>= 1){
        sv += __shfl_xor(sv, o, 64);
        q  += __shfl_xor(q, o, 64);
      }
      float mu = sv*(1.f/64.f);
      float var = fmaf(-mu, mu, q*(1.f/64.f));
      float rs = rsqrtf(var + 1e-5f);
      int rr = rb + quad*4 + r;
      if (rr < nrows){
        float isr2 = isn[rr];
        #pragma unroll
        for (int ot = 0; ot < 4; ++ot){
          float ov = fmaf((pre[ot][r]-mu)*rs, g2l[ot], be2l[ot]);
          Outp[(size_t)rr*64 + ot*16 + n16] = ov;
          Qs[(size_t)rr*64 + ot*16 + n16] = f2bf(ov * isr2);
        }
      }
    }
  }
}

// MFMA final: out = LN(Q, gF, bF) @ Wo + bo
__global__ __launch_bounds__(256) void k_final(const float* __restrict__ Q,
    const unsigned short* __restrict__ WoT, const float* __restrict__ bog,
    const float* __restrict__ gF, const float* __restrict__ bF,
    float* __restrict__ out, int nrows){
  __shared__ unsigned short sWb[64*72];
  int tid = threadIdx.x;
  int lane = tid & 63, w = tid >> 6;
  int quad = lane >> 4, n16 = lane & 15;
  stage64<72>(WoT, sWb, tid, 64);
  __syncthreads();
  int rowbase = blockIdx.x*64 + w*16;
  int arow = min(rowbase + n16, nrows-1);
  float4 q0 = *(const float4*)&Q[(size_t)arow*64 + quad*8];
  float4 q1 = *(const float4*)&Q[(size_t)arow*64 + quad*8 + 4];
  float4 q2 = *(const float4*)&Q[(size_t)arow*64 + 32 + quad*8];
  float4 q3 = *(const float4*)&Q[(size_t)arow*64 + 32 + quad*8 + 4];
  float s = (q0.x+q0.y+q0.z+q0.w) + (q1.x+q1.y+q1.z+q1.w)
          + (q2.x+q2.y+q2.z+q2.w) + (q3.x+q3.y+q3.z+q3.w);
  float qq = (q0.x*q0.x+q0.y*q0.y+q0.z*q0.z+q0.w*q0.w)
           + (q1.x*q1.x+q1.y*q1.y+q1.z*q1.z+q1.w*q1.w)
           + (q2.x*q2.x+q2.y*q2.y+q2.z*q2.z+q2.w*q2.w)
           + (q3.x*q3.x+q3.y*q3.y+q3.z*q3.z+q3.w*q3.w);
  s += __shfl_xor(s, 16, 64);  qq += __shfl_xor(qq, 16, 64);
  s += __shfl_xor(s, 32, 64);  qq += __shfl_xor(qq, 32, 64);
  float mu = s*(1.f/64.f);
  float var = fmaf(-mu, mu, qq*(1.f/64.f));
  float rs = rsqrtf(var + 1e-5f);
  float4 g0 = *(const float4*)&gF[quad*8];
  float4 g1 = *(const float4*)&gF[quad*8 + 4];
  float4 g2 = *(const float4*)&gF[32 + quad*8];
  float4 g3 = *(const float4*)&gF[32 + quad*8 + 4];
  float4 f0 = *(const float4*)&bF[quad*8];
  float4 f1 = *(const float4*)&bF[quad*8 + 4];
  float4 f2 = *(const float4*)&bF[32 + quad*8];
  float4 f3 = *(const float4*)&bF[32 + quad*8 + 4];
  short8 a0, a1;
  a0[0]=f2bf(fmaf((q0.x-mu)*rs, g0.x, f0.x)); a0[1]=f2bf(fmaf((q0.y-mu)*rs, g0.y, f0.y));
  a0[2]=f2bf(fmaf((q0.z-mu)*rs, g0.z, f0.z)); a0[3]=f2bf(fmaf((q0.w-mu)*rs, g0.w, f0.w));
  a0[4]=f2bf(fmaf((q1.x-mu)*rs, g1.x, f1.x)); a0[5]=f2bf(fmaf((q1.y-mu)*rs, g1.y, f1.y));
  a0[6]=f2bf(fmaf((q1.z-mu)*rs, g1.z, f1.z)); a0[7]=f2bf(fmaf((q1.w-mu)*rs, g1.w, f1.w));
  a1[0]=f2bf(fmaf((q2.x-mu)*rs, g2.x, f2.x)); a1[1]=f2bf(fmaf((q2.y-mu)*rs, g2.y, f2.y));
  a1[2]=f2bf(fmaf((q2.z-mu)*rs, g2.z, f2.z)); a1[3]=f2bf(fmaf((q2.w-mu)*rs, g2.w, f2.w));
  a1[4]=f2bf(fmaf((q3.x-mu)*rs, g3.x, f3.x)); a1[5]=f2bf(fmaf((q3.y-mu)*rs, g3.y, f3.y));
  a1[6]=f2bf(fmaf((q3.z-mu)*rs, g3.z, f3.z)); a1[7]=f2bf(fmaf((q3.w-mu)*rs, g3.w, f3.w));
  #pragma unroll
  for (int ot = 0; ot < 4; ++ot){
    floatx4 c = (floatx4){0.f,0.f,0.f,0.f};
    short8 b0 = *(const short8*)&sWb[(ot*16+n16)*72 + quad*8];
    short8 b1 = *(const short8*)&sWb[(ot*16+n16)*72 + 32 + quad*8];
    c = __builtin_amdgcn_mfma_f32_16x16x32_bf16(a0, b0, c, 0, 0, 0);
    c = __builtin_amdgcn_mfma_f32_16x16x32_bf16(a1, b1, c, 0, 0, 0);
    float bol = bog[ot*16 + n16];
    #pragma unroll
    for (int r = 0; r < 4; ++r){
      int rr = rowbase + quad*4 + r;
      if (rr < nrows) out[(size_t)rr*64 + ot*16 + n16] = c[r] + bol;
    }
  }
}

extern "C" void kernel_launch(void* const* d_in, const int* in_sizes, int n_in,
                              void* d_out, int out_size, void* d_ws, size_t ws_size,
                              hipStream_t stream){
  const float* nf   = (const float*)d_in[0];
  const int*   esrc = (const int*)d_in[1];
  const int*   edst = (const int*)d_in[2];
  const float* Wn2h = (const float*)d_in[4];
  const float* bn2h = (const float*)d_in[5];
  const float* Wh2n = (const float*)d_in[6];
  const float* bh2n = (const float*)d_in[7];
  const float* W1   = (const float*)d_in[8];
  const float* b1   = (const float*)d_in[9];
  const float* W2   = (const float*)d_in[10];
  const float* b2   = (const float*)d_in[11];
  const float* g1   = (const float*)d_in[12];
  const float* be1  = (const float*)d_in[13];
  const float* g2   = (const float*)d_in[14];
  const float* be2  = (const float*)d_in[15];
  const float* gF   = (const float*)d_in[16];
  const float* bF   = (const float*)d_in[17];
  const float* Wo   = (const float*)d_in[18];
  const float* bo   = (const float*)d_in[19];
  const int N = in_sizes[0] / 64;
  const int E = in_sizes[1];
  const int H = HYP;
  float* out = (float*)d_out;

  char* w = (char*)d_ws;
  auto carve = [&](size_t bytes) -> char* {
    char* p = w; w += (bytes + 255) & ~(size_t)255; return p;
  };
  int* bh = (int*)carve((size_t)(NB_H + NB_N)*4);
  int* bn = bh + NB_H;
  int* bstart_h = (int*)carve((size_t)(NB_H+1)*4);
  int* gcur_h   = (int*)carve((size_t)NB_H*4);
  int* bstart_n = (int*)carve((size_t)(NB_N+1)*4);
  int* gcur_n   = (int*)carve((size_t)NB_N*4);
  unsigned* Ebuf_h = (unsigned*)carve((size_t)E*4);
  unsigned* Ebuf_n = (unsigned*)carve((size_t)E*4);
  int*   off_h = (int*)carve((size_t)(H+1)*4);
  int*   off_n = (int*)carve((size_t)(N+1)*4);
  float* is_h  = (float*)carve((size_t)H*4);
  float* is_n  = (float*)carve((size_t)N*4);
  int*   csr_h = (int*)carve((size_t)E*4);
  int*   csr_n = (int*)carve((size_t)E*4);
  unsigned short* aggxb = (unsigned short*)carve((size_t)H*64*2);
  unsigned short* agghb = (unsigned short*)carve((size_t)N*64*2);
  float* Qb    = (float*)carve((size_t)N*64*4);
  unsigned short* hhsb = (unsigned short*)carve((size_t)H*64*2);
  unsigned short* xb0  = (unsigned short*)carve((size_t)N*64*2);
  unsigned short* Qs   = (unsigned short*)carve((size_t)N*64*2);
  unsigned short* W1g16 = (unsigned short*)carve((size_t)NLAYER*64*256*2);
  unsigned short* W2g16 = (unsigned short*)carve((size_t)NLAYER*256*64*2);
  unsigned short* Wag16 = (unsigned short*)carve((size_t)NLAYER*4096*2);
  unsigned short* Wbg16 = (unsigned short*)carve((size_t)NLAYER*4096*2);
  unsigned short* Wog16 = (unsigned short*)carve((size_t)4096*2);

  hipMemsetAsync(bh, 0, (size_t)(NB_H + NB_N)*4, stream);
  k_cvtall<<<96, 256, 0, stream>>>(W1, W2, Wn2h, Wh2n, Wo,
                                   W1g16, W2g16, Wag16, Wbg16, Wog16);
  k_hist<<<512, 256, 0, stream>>>(esrc, edst, E, bh, bn);
  k_bscan<<<1, 256, 0, stream>>>(bh, bn, bstart_h, gcur_h, bstart_n, gcur_n);
  const int nblk = (E + PT - 1)/PT;
  k_partition2<<<2*nblk, 256, 0, stream>>>(esrc, edst, E, nblk,
                                           gcur_h, Ebuf_h, gcur_n, Ebuf_n);
  k_build2<<<NB_H + NB_N, 256, 0, stream>>>(Ebuf_h, bstart_h, Ebuf_n, bstart_n,
                                            off_h, is_h, csr_h,
                                            off_n, is_n, csr_n,
                                            nf, xb0, H, N);

  const int NB64 = (N + 63)/64;
  const int HB64 = (H + 63)/64;
  for (int l = 0; l < NLAYER; ++l){
    const float* hin = (l == 0) ? nf : Qb;
    const unsigned short* hsrc = (l == 0) ? xb0 : Qs;
    k_gather8<<<2048, 256, 0, stream>>>(hsrc, csr_h, off_h, aggxb, H);
    k_mmA<<<HB64, 256, 0, stream>>>(aggxb, Wag16 + l*4096, bn2h + l*64, is_h, hhsb, H);
    k_gatherN<<<2048, 256, 0, stream>>>(hhsb, csr_n, off_n, agghb, N);
    k_fused<<<256, 1024, 0, stream>>>(agghb, Wbg16 + l*4096, bh2n + l*64, is_n, hin,
                                      g1 + l*64, be1 + l*64,
                                      W1g16 + l*64*256, b1 + l*256,
                                      W2g16 + l*256*64, b2 + l*64,
                                      g2 + l*64, be2 + l*64, Qb, Qs, N);
  }
  k_final<<<NB64, 256, 0, stream>>>(Qb, Wog16, bo, gF, bF, out, N);
}